// Round 3
// baseline (2265.520 us; speedup 1.0000x reference)
//
#include <hip/hip_runtime.h>
#include <math.h>

#define BB 4
#define NP 8192
#define CF 64
#define MQ 2048
#define KS 32

// ---- workspace layout (float indices) ----
#define WS_FT     0u         // ft: [B][N][64] transposed features (2097152 floats)
#define WS_NIDX   2097152u   // nidx: [B][M][K] int (262144)
#define WS_IDXI   2359296u   // idx int copy: [B][M] (8192)
#define WS_ST1    2367488u   // stats1 slices: [64][2][64] (8192)
#define WS_ST2    2375680u   // stats2 slices: [64][2][128] (16384)
#define WS_SC1    2392064u   // scale/shift bn1: [2][64] (128)
#define WS_SC2    2392192u   // scale/shift bn2: [2][128] (256)
#define WS_MAXY2  2392448u   // maxy2: [B*M][128] (1048576)
#define WS_W1P    3441024u   // padded w1: [64][68] (4352)

typedef float v2f __attribute__((ext_vector_type(2)));

// ------------------------------------------------------------------
// transpose f [B][64][N] -> ft [B][N][64]
// ------------------------------------------------------------------
__global__ __launch_bounds__(256) void transpose_f_kernel(
    const float* __restrict__ f, float* __restrict__ ft) {
  __shared__ float tile[64][65];
  int b = blockIdx.y;
  int n0 = blockIdx.x * 64;
  int cc = threadIdx.x >> 6;   // 0..3
  int nn = threadIdx.x & 63;
  #pragma unroll
  for (int r = 0; r < 16; ++r) {
    int c = cc * 16 + r;
    tile[c][nn] = f[((size_t)b * 64 + c) * NP + n0 + nn];
  }
  __syncthreads();
  #pragma unroll
  for (int r = 0; r < 16; ++r) {
    int nl = cc * 16 + r;
    ft[((size_t)b * NP + n0 + nl) * 64 + nn] = tile[nn][nl];
  }
}

// ------------------------------------------------------------------
// pad w1 [64][67] -> w1p [64][68] (last col 0), 16B-aligned rows
// ------------------------------------------------------------------
__global__ void prep_w1_kernel(const float* __restrict__ w1, float* __restrict__ w1p) {
  int i = blockIdx.x * 256 + threadIdx.x;
  if (i < 64 * 68) {
    int o = i / 68, c = i % 68;
    w1p[i] = (c < 67) ? w1[o * 67 + c] : 0.0f;
  }
}

// ------------------------------------------------------------------
// FPS v8: v7 measurements -> kernel is VALU-ISSUE-bound (VALUBusy
// ~70% of active CUs, ~1300 cyc/iter of issue at 1880 cyc/iter;
// round-1 proved extra waves don't help). Instr estimate says the
// compiler SCALARIZES the v2f scan (CDNA4 has no v_pk_min_f32, and
// the .x/.y extracts feeding the scalar argmax split the pairs).
// v8 forces the packable 8 ops/k into true VOP3P packed f32 via
// inline asm: v_pk_add_f32 (sub done as add of pre-negated center:
// IEEE x-y == x+(-y) exactly) and v_pk_mul_f32 (both = 2 independent
// IEEE-rn f32 ops -> bit-identical to the scalar sequence). min stays
// scalar v_min_f32 (fminf; == elementwise_min on these non-NaN
// inputs); dmin kept as 32 scalars to avoid pair-copy churn.
// Dual strict-> argmax chains, u64 key (f32bits(dmin)<<32)|~idx, DPP
// wave-max (row_shr 1/2/4/8 + bcast15/31), per-wave key slots +
// double buffer + local 4-key merge: unchanged from v7.
// ------------------------------------------------------------------
#define FPS_T 256
#define PPT 32

__device__ __forceinline__ v2f pk_add(v2f a, v2f b) {
  v2f d;
  asm("v_pk_add_f32 %0, %1, %2" : "=v"(d) : "v"(a), "v"(b));
  return d;
}
__device__ __forceinline__ v2f pk_mul(v2f a, v2f b) {
  v2f d;
  asm("v_pk_mul_f32 %0, %1, %2" : "=v"(d) : "v"(a), "v"(b));
  return d;
}

template <int CTRL>
__device__ __forceinline__ unsigned long long dpp_max_step(unsigned long long k) {
  int lo = (int)(unsigned)k;
  int hi = (int)(unsigned)(k >> 32);
  int slo = __builtin_amdgcn_update_dpp(0, lo, CTRL, 0xF, 0xF, true);
  int shi = __builtin_amdgcn_update_dpp(0, hi, CTRL, 0xF, 0xF, true);
  unsigned long long s =
      ((unsigned long long)(unsigned)shi << 32) | (unsigned long long)(unsigned)slo;
  return s > k ? s : k;
}

__global__ __launch_bounds__(256, 1) void fps_kernel(
    const float* __restrict__ p, float* __restrict__ out, int* __restrict__ idx_i) {
#pragma clang fp contract(off)
  __shared__ float4 sp4[NP];                 // 128 KB: xyz + pad
  __shared__ int win[MQ];                    // 8 KB winner indices
  __shared__ __align__(16) unsigned long long wkey[2][4];  // per-wave key slots, dbuf
  int b = blockIdx.x;
  const float* pb = p + (size_t)b * NP * 3;
  float* out_newp = out;                               // [B][M][3]
  float* out_idxf = out + BB*MQ*3 + (size_t)BB*128*MQ; // [B][M] as float
  int t = threadIdx.x;

  v2f px2[16], py2[16], pz2[16];
  float dmn0[16], dmn1[16];                  // even-slot / odd-slot dmin (scalar)
  #pragma unroll
  for (int k = 0; k < 16; ++k) {
    int i0 = (2*k) * FPS_T + t;
    int i1 = i0 + FPS_T;
    float x0 = pb[i0*3+0], y0 = pb[i0*3+1], z0 = pb[i0*3+2];
    float x1 = pb[i1*3+0], y1 = pb[i1*3+1], z1 = pb[i1*3+2];
    px2[k] = (v2f){x0, x1}; py2[k] = (v2f){y0, y1}; pz2[k] = (v2f){z0, z1};
    sp4[i0] = make_float4(x0, y0, z0, 0.0f);
    sp4[i1] = make_float4(x1, y1, z1, 0.0f);
    dmn0[k] = INFINITY; dmn1[k] = INFINITY;
  }
  if (t == 0) win[0] = 0;
  __syncthreads();
  float lx = sp4[0].x, ly = sp4[0].y, lz = sp4[0].z;
  unsigned nt = ~(unsigned)t;

  for (int j = 1; j < MQ; ++j) {
#pragma clang fp contract(off)
    // packed negated center: x - l == x + (-l) exactly (IEEE)
    v2f nlx = (v2f){-lx, -lx}, nly = (v2f){-ly, -ly}, nlz = (v2f){-lz, -lz};
    // dual strict-> argmax chains: chain0 = even slots (.x), chain1 = odd (.y)
    float bv0 = -1.0f, bv1 = -1.0f;
    unsigned bn0 = 0u, bn1 = 0u;
    #pragma unroll
    for (int k = 0; k < 16; ++k) {
      v2f dx = pk_add(px2[k], nlx);
      v2f dy = pk_add(py2[k], nly);
      v2f dz = pk_add(pz2[k], nlz);
      v2f dd = pk_add(pk_add(pk_mul(dx, dx), pk_mul(dy, dy)), pk_mul(dz, dz));
      float m0 = fminf(dmn0[k], dd.x);  dmn0[k] = m0;
      float m1 = fminf(dmn1[k], dd.y);  dmn1[k] = m1;
      bool g0 = m0 > bv0;                 // strict > keeps earliest slot
      bv0 = g0 ? m0 : bv0;
      bn0 = g0 ? (nt - (unsigned)((2*k) * FPS_T)) : bn0;      // ~((2k)*256+t)
      bool g1 = m1 > bv1;
      bv1 = g1 ? m1 : bv1;
      bn1 = g1 ? (nt - (unsigned)((2*k+1) * FPS_T)) : bn1;    // ~((2k+1)*256+t)
    }
    unsigned long long k0 =
        ((unsigned long long)__float_as_uint(bv0) << 32) | (unsigned long long)bn0;
    unsigned long long k1 =
        ((unsigned long long)__float_as_uint(bv1) << 32) | (unsigned long long)bn1;
    unsigned long long key = k0 > k1 ? k0 : k1;   // ties: larger ~idx = smaller idx
    // DPP wave-max: result lands in lane 63
    key = dpp_max_step<0x111>(key);  // row_shr:1
    key = dpp_max_step<0x112>(key);  // row_shr:2
    key = dpp_max_step<0x114>(key);  // row_shr:4
    key = dpp_max_step<0x118>(key);  // row_shr:8
    key = dpp_max_step<0x142>(key);  // row_bcast15
    key = dpp_max_step<0x143>(key);  // row_bcast31
    if ((t & 63) == 63) wkey[j & 1][t >> 6] = key;   // 4 parallel slot writes
    __syncthreads();                 // single barrier per iteration
    const ulonglong2* wk2 = (const ulonglong2*)(&wkey[j & 1][0]);
    ulonglong2 ka = wk2[0];          // broadcast ds_read_b128
    ulonglong2 kb = wk2[1];
    unsigned long long m0 = ka.x > ka.y ? ka.x : ka.y;
    unsigned long long m1 = kb.x > kb.y ? kb.x : kb.y;
    unsigned long long kw = m0 > m1 ? m0 : m1;
    int wi = (int)(~(unsigned)kw);
    float4 c = sp4[wi];              // one ds_read_b128, same-addr broadcast
    lx = c.x; ly = c.y; lz = c.z;
    if (t == 0) win[j] = wi;
  }

  __syncthreads();
  // bulk coalesced epilogue: idx (float + int) and new_p from LDS
  #pragma unroll
  for (int k = 0; k < MQ / FPS_T; ++k) {
    int j = k * FPS_T + t;
    int wi = win[j];
    out_idxf[b*MQ + j] = (float)wi;
    idx_i[b*MQ + j] = wi;
    float4 c = sp4[wi];
    float* np_ = &out_newp[(size_t)(b*MQ + j) * 3];
    np_[0] = c.x; np_[1] = c.y; np_[2] = c.z;
  }
}

// ------------------------------------------------------------------
// ball query: one wave per query. Mirrors |q|^2+|p|^2-2*dot with rn
// ops; threshold is float( double(0.1)*double(0.1) ).
// ------------------------------------------------------------------
__global__ __launch_bounds__(256) void ballq_kernel(
    const float* __restrict__ p, const float* __restrict__ newp,
    int* __restrict__ nidx) {
  int qid = blockIdx.x * 4 + (threadIdx.x >> 6);   // b*M+m
  int lane = threadIdx.x & 63;
  int b = qid >> 11;
  const float* pb = p + (size_t)b * NP * 3;
  float qx = newp[qid*3], qy = newp[qid*3+1], qz = newp[qid*3+2];
  float sq_q = __fadd_rn(__fadd_rn(__fmul_rn(qx,qx), __fmul_rn(qy,qy)), __fmul_rn(qz,qz));
  const float R2 = (float)(0.1 * 0.1);   // 0.009999999776482582f
  int found = 0, first = -1;
  int* outp = nidx + (size_t)qid * KS;
  for (int base = 0; base < NP; base += 64) {
    int n = base + lane;
    float x = pb[n*3], y = pb[n*3+1], z = pb[n*3+2];
    float sq_p = __fadd_rn(__fadd_rn(__fmul_rn(x,x), __fmul_rn(y,y)), __fmul_rn(z,z));
    float dot  = __fadd_rn(__fadd_rn(__fmul_rn(qx,x), __fmul_rn(qy,y)), __fmul_rn(qz,z));
    float d2   = __fadd_rn(__fadd_rn(sq_q, sq_p), __fmul_rn(-2.0f, dot));
    bool hit = d2 < R2;
    unsigned long long mask = __ballot(hit);
    if (mask) {
      if (first < 0) first = base + __builtin_ctzll(mask);
      int cnt = __popcll(mask);
      if (found < KS) {
        int rank = __popcll(mask & ((1ull << lane) - 1ull));
        if (hit && found + rank < KS) outp[found + rank] = n;
      }
      found += cnt;
      if (found >= KS) break;
    }
  }
  int fcl = found < KS ? found : KS;
  int padv = first < 0 ? 0 : first;
  if (lane >= fcl && lane < KS) outp[lane] = padv;
}

// ------------------------------------------------------------------
// P1: conv1 over gathered x, accumulate per-channel sum/sumsq.
// One wave per query, lane = output channel.
// ------------------------------------------------------------------
__global__ __launch_bounds__(256) void p1_kernel(
    const float* __restrict__ p, const float* __restrict__ newp,
    const float* __restrict__ ft, const int* __restrict__ nidx,
    const float* __restrict__ w1p, float* __restrict__ stats1) {
  __shared__ __align__(16) float xbuf[4][KS][68];
  __shared__ float wbs[4][64], wbq[4][64];
  int wv = threadIdx.x >> 6, lane = threadIdx.x & 63;
  int qid = blockIdx.x * 4 + wv;
  int b = qid >> 11;
  // gather x = [dp(3) | fj(64) | 0]
  int nv = (lane < KS) ? nidx[(size_t)qid * KS + lane] : 0;
  float qx = newp[qid*3], qy = newp[qid*3+1], qz = newp[qid*3+2];
  for (int kk = 0; kk < KS; ++kk) {
    int n = __shfl(nv, kk);
    const float* fr = ft + ((size_t)b * NP + n) * 64;
    xbuf[wv][kk][3 + lane] = fr[lane];
    if (lane < 3) {
      const float* pp = p + ((size_t)b * NP + n) * 3;
      float qc = (lane == 0) ? qx : ((lane == 1) ? qy : qz);
      xbuf[wv][kk][lane] = __fsub_rn(pp[lane], qc);
    }
    if (lane == 3) xbuf[wv][kk][67] = 0.0f;
  }
  __syncthreads();
  // conv1: lane = channel o; preload its w row into regs
  const float4* wr = (const float4*)(w1p + lane * 68);
  float4 wreg[17];
  #pragma unroll
  for (int c4 = 0; c4 < 17; ++c4) wreg[c4] = wr[c4];
  float ss = 0.f, qq = 0.f;
  for (int kk = 0; kk < KS; ++kk) {
    const float4* xr = (const float4*)(&xbuf[wv][kk][0]);
    float acc = 0.f;
    #pragma unroll
    for (int c4 = 0; c4 < 17; ++c4) {
      float4 w = wreg[c4]; float4 x = xr[c4];
      acc += w.x*x.x + w.y*x.y + w.z*x.z + w.w*x.w;
    }
    ss += acc; qq += acc * acc;
  }
  wbs[wv][lane] = ss; wbq[wv][lane] = qq;
  __syncthreads();
  if (threadIdx.x < 64) {
    float s  = wbs[0][threadIdx.x] + wbs[1][threadIdx.x] + wbs[2][threadIdx.x] + wbs[3][threadIdx.x];
    float s2 = wbq[0][threadIdx.x] + wbq[1][threadIdx.x] + wbq[2][threadIdx.x] + wbq[3][threadIdx.x];
    int slice = blockIdx.x & 63;
    atomicAdd(&stats1[(slice*2+0)*64 + threadIdx.x], s);
    atomicAdd(&stats1[(slice*2+1)*64 + threadIdx.x], s2);
  }
}

// ------------------------------------------------------------------
// finalize bn1 stats -> scale/shift
// ------------------------------------------------------------------
__global__ void fin1_kernel(const float* __restrict__ stats1,
                            const float* __restrict__ g, const float* __restrict__ bb,
                            float* __restrict__ sc) {
  int o = threadIdx.x;  // 64
  float s = 0.f, q = 0.f;
  for (int sl = 0; sl < 64; ++sl) { s += stats1[(sl*2+0)*64+o]; q += stats1[(sl*2+1)*64+o]; }
  const float cnt = (float)(BB * MQ * KS);
  float mean = s / cnt;
  float var = q / cnt - mean * mean;
  float rstd = 1.0f / sqrtf(var + 1e-5f);
  float gs = g[o] * rstd;
  sc[o] = gs;
  sc[64+o] = bb[o] - mean * gs;
}

__global__ void fin2_kernel(const float* __restrict__ stats2,
                            const float* __restrict__ g, const float* __restrict__ bb,
                            float* __restrict__ sc) {
  int o = threadIdx.x;  // 128
  float s = 0.f, q = 0.f;
  for (int sl = 0; sl < 64; ++sl) { s += stats2[(sl*2+0)*128+o]; q += stats2[(sl*2+1)*128+o]; }
  const float cnt = (float)(BB * MQ * KS);
  float mean = s / cnt;
  float var = q / cnt - mean * mean;
  float rstd = 1.0f / sqrtf(var + 1e-5f);
  float gs = g[o] * rstd;
  sc[o] = gs;
  sc[128+o] = bb[o] - mean * gs;
}

// ------------------------------------------------------------------
// P2: recompute conv1, bn1+relu (h overwrites x rows in LDS), conv2,
// per-channel stats2 + per-query max over K (bn2 commutes with max).
// ------------------------------------------------------------------
__global__ __launch_bounds__(256) void p2_kernel(
    const float* __restrict__ p, const float* __restrict__ newp,
    const float* __restrict__ ft, const int* __restrict__ nidx,
    const float* __restrict__ w1p, const float* __restrict__ w2,
    const float* __restrict__ sc1,
    float* __restrict__ stats2, float* __restrict__ maxy2) {
  __shared__ __align__(16) float xbuf[4][KS][68];
  __shared__ float wbs[4][128], wbq[4][128];
  int wv = threadIdx.x >> 6, lane = threadIdx.x & 63;
  int qid = blockIdx.x * 4 + wv;
  int b = qid >> 11;
  // gather
  int nv = (lane < KS) ? nidx[(size_t)qid * KS + lane] : 0;
  float qx = newp[qid*3], qy = newp[qid*3+1], qz = newp[qid*3+2];
  for (int kk = 0; kk < KS; ++kk) {
    int n = __shfl(nv, kk);
    const float* fr = ft + ((size_t)b * NP + n) * 64;
    xbuf[wv][kk][3 + lane] = fr[lane];
    if (lane < 3) {
      const float* pp = p + ((size_t)b * NP + n) * 3;
      float qc = (lane == 0) ? qx : ((lane == 1) ? qy : qz);
      xbuf[wv][kk][lane] = __fsub_rn(pp[lane], qc);
    }
    if (lane == 3) xbuf[wv][kk][67] = 0.0f;
  }
  __syncthreads();
  // conv1 + bn1 + relu; h[o=lane][kk] written into xbuf[wv][kk][lane]
  {
    const float4* wr = (const float4*)(w1p + lane * 68);
    float4 wreg[17];
    #pragma unroll
    for (int c4 = 0; c4 < 17; ++c4) wreg[c4] = wr[c4];
    float s1v = sc1[lane], t1v = sc1[64 + lane];
    for (int kk = 0; kk < KS; ++kk) {
      const float4* xr = (const float4*)(&xbuf[wv][kk][0]);
      float acc = 0.f;
      #pragma unroll
      for (int c4 = 0; c4 < 17; ++c4) {
        float4 w = wreg[c4]; float4 x = xr[c4];
        acc += w.x*x.x + w.y*x.y + w.z*x.z + w.w*x.w;
      }
      float h = fmaxf(0.0f, fmaf(acc, s1v, t1v));
      xbuf[wv][kk][lane] = h;   // safe: whole row kk consumed by all lanes (lockstep)
    }
  }
  // conv2: lane computes channels lane and lane+64
  const float4* w2a = (const float4*)(w2 + (size_t)lane * 64);
  const float4* w2b = (const float4*)(w2 + (size_t)(lane + 64) * 64);
  float4 wra[16], wrb[16];
  #pragma unroll
  for (int c4 = 0; c4 < 16; ++c4) { wra[c4] = w2a[c4]; wrb[c4] = w2b[c4]; }
  float ss0 = 0.f, qq0 = 0.f, mx0 = -INFINITY;
  float ss1 = 0.f, qq1 = 0.f, mx1 = -INFINITY;
  for (int kk = 0; kk < KS; ++kk) {
    const float4* hr = (const float4*)(&xbuf[wv][kk][0]);
    float a0 = 0.f, a1 = 0.f;
    #pragma unroll
    for (int c4 = 0; c4 < 16; ++c4) {
      float4 h4 = hr[c4];
      float4 wa = wra[c4]; float4 wb = wrb[c4];
      a0 += wa.x*h4.x + wa.y*h4.y + wa.z*h4.z + wa.w*h4.w;
      a1 += wb.x*h4.x + wb.y*h4.y + wb.z*h4.z + wb.w*h4.w;
    }
    ss0 += a0; qq0 += a0*a0; mx0 = fmaxf(mx0, a0);
    ss1 += a1; qq1 += a1*a1; mx1 = fmaxf(mx1, a1);
  }
  maxy2[(size_t)qid * 128 + lane] = mx0;
  maxy2[(size_t)qid * 128 + 64 + lane] = mx1;
  wbs[wv][lane] = ss0; wbs[wv][64+lane] = ss1;
  wbq[wv][lane] = qq0; wbq[wv][64+lane] = qq1;
  __syncthreads();
  if (threadIdx.x < 128) {
    float s  = wbs[0][threadIdx.x] + wbs[1][threadIdx.x] + wbs[2][threadIdx.x] + wbs[3][threadIdx.x];
    float s2 = wbq[0][threadIdx.x] + wbq[1][threadIdx.x] + wbq[2][threadIdx.x] + wbq[3][threadIdx.x];
    int slice = blockIdx.x & 63;
    atomicAdd(&stats2[(slice*2+0)*128 + threadIdx.x], s);
    atomicAdd(&stats2[(slice*2+1)*128 + threadIdx.x], s2);
  }
}

// ------------------------------------------------------------------
// P3: skip conv (w_skip · f[:,idx] + b_skip) + bn2 affine on max + relu
// ------------------------------------------------------------------
__global__ __launch_bounds__(256) void p3_kernel(
    const float* __restrict__ ft, const int* __restrict__ idx_i,
    const float* __restrict__ w_skip, const float* __restrict__ b_skip,
    const float* __restrict__ sc2, const float* __restrict__ maxy2,
    float* __restrict__ outf) {
  int wv = threadIdx.x >> 6, lane = threadIdx.x & 63;
  int qid = blockIdx.x * 4 + wv;
  int b = qid >> 11, m = qid & (MQ - 1);
  int n = idx_i[qid];
  const float4* f4 = (const float4*)(ft + ((size_t)b * NP + n) * 64);
  const float4* wa = (const float4*)(w_skip + (size_t)lane * 64);
  const float4* wb = (const float4*)(w_skip + (size_t)(lane + 64) * 64);
  float a0 = b_skip[lane], a1 = b_skip[lane + 64];
  #pragma unroll
  for (int c4 = 0; c4 < 16; ++c4) {
    float4 x = f4[c4]; float4 u = wa[c4]; float4 v = wb[c4];
    a0 += u.x*x.x + u.y*x.y + u.z*x.z + u.w*x.w;
    a1 += v.x*x.x + v.y*x.y + v.z*x.z + v.w*x.w;
  }
  float v0 = maxy2[(size_t)qid * 128 + lane];
  float v1 = maxy2[(size_t)qid * 128 + 64 + lane];
  float r0 = fmaxf(0.0f, fmaf(v0, sc2[lane],      sc2[128 + lane])      + a0);
  float r1 = fmaxf(0.0f, fmaf(v1, sc2[lane + 64], sc2[128 + lane + 64]) + a1);
  outf[((size_t)b * 128 + lane) * MQ + m] = r0;
  outf[((size_t)b * 128 + lane + 64) * MQ + m] = r1;
}

// ------------------------------------------------------------------
extern "C" void kernel_launch(void* const* d_in, const int* in_sizes, int n_in,
                              void* d_out, int out_size, void* d_ws, size_t ws_size,
                              hipStream_t stream) {
  (void)in_sizes; (void)n_in; (void)out_size; (void)ws_size;
  const float* p   = (const float*)d_in[0];
  const float* f   = (const float*)d_in[1];
  const float* w1  = (const float*)d_in[2];
  const float* g1  = (const float*)d_in[3];
  const float* b1  = (const float*)d_in[4];
  const float* w2  = (const float*)d_in[5];
  const float* g2  = (const float*)d_in[6];
  const float* b2  = (const float*)d_in[7];
  const float* wsk = (const float*)d_in[8];
  const float* bsk = (const float*)d_in[9];
  float* out = (float*)d_out;
  float* wsf = (float*)d_ws;

  float* ft    = wsf + WS_FT;
  int*   nidx  = (int*)(wsf + WS_NIDX);
  int*   idxi  = (int*)(wsf + WS_IDXI);
  float* st1   = wsf + WS_ST1;
  float* st2   = wsf + WS_ST2;
  float* sc1   = wsf + WS_SC1;
  float* sc2   = wsf + WS_SC2;
  float* maxy2 = wsf + WS_MAXY2;
  float* w1p   = wsf + WS_W1P;

  float* out_newp = out;
  float* out_f    = out + BB*MQ*3;

  // zero the atomic stats accumulators (st1+st2 are contiguous)
  (void)hipMemsetAsync(st1, 0, (8192 + 16384) * sizeof(float), stream);

  transpose_f_kernel<<<dim3(NP/64, BB), 256, 0, stream>>>(f, ft);
  prep_w1_kernel<<<17, 256, 0, stream>>>(w1, w1p);
  fps_kernel<<<BB, FPS_T, 0, stream>>>(p, out, idxi);
  ballq_kernel<<<BB*MQ/4, 256, 0, stream>>>(p, out_newp, nidx);
  p1_kernel<<<BB*MQ/4, 256, 0, stream>>>(p, out_newp, ft, nidx, w1p, st1);
  fin1_kernel<<<1, 64, 0, stream>>>(st1, g1, b1, sc1);
  p2_kernel<<<BB*MQ/4, 256, 0, stream>>>(p, out_newp, ft, nidx, w1p, w2, sc1, st2, maxy2);
  fin2_kernel<<<1, 128, 0, stream>>>(st2, g2, b2, sc2);
  p3_kernel<<<BB*MQ/4, 256, 0, stream>>>(ft, idxi, wsk, bsk, sc2, maxy2, out_f);
}

// Round 4
// 2250.007 us; speedup vs baseline: 1.0069x; 1.0069x over previous
//
#include <hip/hip_runtime.h>
#include <math.h>

#define BB 4
#define NP 8192
#define CF 64
#define MQ 2048
#define KS 32

// ---- workspace layout (float indices) ----
#define WS_FT     0u         // ft: [B][N][64] transposed features (2097152 floats)
#define WS_NIDX   2097152u   // nidx: [B][M][K] int (262144)
#define WS_IDXI   2359296u   // idx int copy: [B][M] (8192)
#define WS_ST1    2367488u   // stats1 slices: [64][2][64] (8192)
#define WS_ST2    2375680u   // stats2 slices: [64][2][128] (16384)
#define WS_SC1    2392064u   // scale/shift bn1: [2][64] (128)
#define WS_SC2    2392192u   // scale/shift bn2: [2][128] (256)
#define WS_MAXY2  2392448u   // maxy2: [B*M][128] (1048576)
#define WS_W1P    3441024u   // padded w1: [64][68] (4352)

typedef float v2f __attribute__((ext_vector_type(2)));

// ------------------------------------------------------------------
// FPS v9 (fused dispatch): blocks 0..3 = FPS, 4..515 = transpose of
// f [B][64][N] -> ft [B][N][64], 516.. = w1 pad. transpose/prep don't
// depend on FPS; folding them into the FPS dispatch runs them on the
// 252 idle CUs under FPS's 1.3+ms shadow instead of serializing on
// the stream.
//
// FPS sizing history (measured):
//   256 thr / 32 pts (v7): 1603 us. VGPR=132 but ~150 live needed
//     (96 coord + 32 dmin + ~20 work) -> allocator mov/remat churn;
//     VALUBusy says ~650 inst/iter vs ~310 ideal.
//   1024 thr / 8 pts (v6): 2062 us. per-SIMD overhead (key+DPP+merge
//     ~95 inst/wave) replicated 4x/SIMD + 16 serialized atomics.
//   pk-asm (v8): 1800 us. asm constraints forced copies. REVERTED.
// v9: 512 thr / 16 pts = 8 v2f pairs: coords 48 VGPR + dmin 16 ->
// ~80 live, churn gone; overhead only 2x/SIMD; argmax chain len 8.
// Selection bit-identical: same per-point FP ops in same order, same
// u64 key (f32bits(dmin)<<32)|~idx (~(s*512+t) == ~t - s*512,
// carry-free), same DPP wave-max, 8-slot double-buffered merge.
// ------------------------------------------------------------------
#define FPS_T 512
#define FPS_NK 8     // v2f pairs per thread: 16 points/thread

template <int CTRL>
__device__ __forceinline__ unsigned long long dpp_max_step(unsigned long long k) {
  int lo = (int)(unsigned)k;
  int hi = (int)(unsigned)(k >> 32);
  int slo = __builtin_amdgcn_update_dpp(0, lo, CTRL, 0xF, 0xF, true);
  int shi = __builtin_amdgcn_update_dpp(0, hi, CTRL, 0xF, 0xF, true);
  unsigned long long s =
      ((unsigned long long)(unsigned)shi << 32) | (unsigned long long)(unsigned)slo;
  return s > k ? s : k;
}

// LDS pool: fps uses sp4[NP] (128KB) + win[MQ] (8KB) + wkey (128B);
// transpose uses tile[64][65] (16.6KB). Shared via one aligned pool.
__global__ __launch_bounds__(512, 1) void fps_fused_kernel(
    const float* __restrict__ p, float* __restrict__ out, int* __restrict__ idx_i,
    const float* __restrict__ f, float* __restrict__ ft,
    const float* __restrict__ w1, float* __restrict__ w1p) {
#pragma clang fp contract(off)
  __shared__ __align__(16) char smem[NP * 16 + MQ * 4 + 2 * 8 * 8];
  int bx = blockIdx.x;
  int t = threadIdx.x;

  if (bx >= 4) {
    if (bx < 4 + 512) {
      // ---- transpose block: tb = bx-4; b = tb>>7, n0 = (tb&127)*64
      float (*tile)[65] = (float (*)[65])smem;
      int tb = bx - 4;
      int b = tb >> 7;
      int n0 = (tb & 127) * 64;
      int cc = t >> 6;        // 0..7
      int nn = t & 63;
      #pragma unroll
      for (int r = 0; r < 8; ++r) {
        int c = cc * 8 + r;
        tile[c][nn] = f[((size_t)b * 64 + c) * NP + n0 + nn];
      }
      __syncthreads();
      #pragma unroll
      for (int r = 0; r < 8; ++r) {
        int nl = cc * 8 + r;
        ft[((size_t)b * NP + n0 + nl) * 64 + nn] = tile[nn][nl];
      }
    } else {
      // ---- w1 pad block
      int i = (bx - 516) * 512 + t;
      if (i < 64 * 68) {
        int o = i / 68, c = i % 68;
        w1p[i] = (c < 67) ? w1[o * 67 + c] : 0.0f;
      }
    }
    return;
  }

  // ---------------- FPS body (blocks 0..3) ----------------
  float4* sp4 = (float4*)smem;                                   // [NP]
  int* win = (int*)(smem + NP * 16);                             // [MQ]
  unsigned long long* wkey = (unsigned long long*)(smem + NP * 16 + MQ * 4); // [2][8]

  int b = bx;
  const float* pb = p + (size_t)b * NP * 3;
  float* out_newp = out;                               // [B][M][3]
  float* out_idxf = out + BB*MQ*3 + (size_t)BB*128*MQ; // [B][M] as float

  v2f px2[FPS_NK], py2[FPS_NK], pz2[FPS_NK];
  float dmn0[FPS_NK], dmn1[FPS_NK];          // even-slot / odd-slot dmin
  #pragma unroll
  for (int k = 0; k < FPS_NK; ++k) {
    int i0 = (2*k) * FPS_T + t;
    int i1 = i0 + FPS_T;
    float x0 = pb[i0*3+0], y0 = pb[i0*3+1], z0 = pb[i0*3+2];
    float x1 = pb[i1*3+0], y1 = pb[i1*3+1], z1 = pb[i1*3+2];
    px2[k] = (v2f){x0, x1}; py2[k] = (v2f){y0, y1}; pz2[k] = (v2f){z0, z1};
    sp4[i0] = make_float4(x0, y0, z0, 0.0f);
    sp4[i1] = make_float4(x1, y1, z1, 0.0f);
    dmn0[k] = INFINITY; dmn1[k] = INFINITY;
  }
  if (t == 0) win[0] = 0;
  __syncthreads();
  float lx = sp4[0].x, ly = sp4[0].y, lz = sp4[0].z;
  unsigned nt = ~(unsigned)t;

  for (int j = 1; j < MQ; ++j) {
#pragma clang fp contract(off)
    v2f l2x = (v2f){lx, lx}, l2y = (v2f){ly, ly}, l2z = (v2f){lz, lz};
    // dual strict-> argmax chains: chain0 = even slots (.x), chain1 = odd (.y)
    float bv0 = -1.0f, bv1 = -1.0f;
    unsigned bn0 = 0u, bn1 = 0u;
    #pragma unroll
    for (int k = 0; k < FPS_NK; ++k) {
      v2f dx = px2[k] - l2x;
      v2f dy = py2[k] - l2y;
      v2f dz = pz2[k] - l2z;
      v2f dd = ((dx*dx) + (dy*dy)) + (dz*dz);
      float m0 = fminf(dmn0[k], dd.x);  dmn0[k] = m0;
      float m1 = fminf(dmn1[k], dd.y);  dmn1[k] = m1;
      bool g0 = m0 > bv0;                 // strict > keeps earliest slot
      bv0 = g0 ? m0 : bv0;
      bn0 = g0 ? (nt - (unsigned)((2*k) * FPS_T)) : bn0;      // ~((2k)*512+t)
      bool g1 = m1 > bv1;
      bv1 = g1 ? m1 : bv1;
      bn1 = g1 ? (nt - (unsigned)((2*k+1) * FPS_T)) : bn1;    // ~((2k+1)*512+t)
    }
    unsigned long long k0 =
        ((unsigned long long)__float_as_uint(bv0) << 32) | (unsigned long long)bn0;
    unsigned long long k1 =
        ((unsigned long long)__float_as_uint(bv1) << 32) | (unsigned long long)bn1;
    unsigned long long key = k0 > k1 ? k0 : k1;   // ties: larger ~idx = smaller idx
    // DPP wave-max: result lands in lane 63
    key = dpp_max_step<0x111>(key);  // row_shr:1
    key = dpp_max_step<0x112>(key);  // row_shr:2
    key = dpp_max_step<0x114>(key);  // row_shr:4
    key = dpp_max_step<0x118>(key);  // row_shr:8
    key = dpp_max_step<0x142>(key);  // row_bcast15
    key = dpp_max_step<0x143>(key);  // row_bcast31
    if ((t & 63) == 63) wkey[(j & 1) * 8 + (t >> 6)] = key;   // 8 parallel slot writes
    __syncthreads();                 // single barrier per iteration
    const ulonglong2* wk2 = (const ulonglong2*)(&wkey[(j & 1) * 8]);
    ulonglong2 a0 = wk2[0];          // broadcast ds_read_b128 x4
    ulonglong2 a1 = wk2[1];
    ulonglong2 a2 = wk2[2];
    ulonglong2 a3 = wk2[3];
    unsigned long long m0 = a0.x > a0.y ? a0.x : a0.y;
    unsigned long long m1 = a1.x > a1.y ? a1.x : a1.y;
    unsigned long long m2 = a2.x > a2.y ? a2.x : a2.y;
    unsigned long long m3 = a3.x > a3.y ? a3.x : a3.y;
    unsigned long long ma = m0 > m1 ? m0 : m1;
    unsigned long long mb = m2 > m3 ? m2 : m3;
    unsigned long long kw = ma > mb ? ma : mb;
    int wi = (int)(~(unsigned)kw);
    float4 c = sp4[wi];              // one ds_read_b128, same-addr broadcast
    lx = c.x; ly = c.y; lz = c.z;
    if (t == 0) win[j] = wi;
  }

  __syncthreads();
  // bulk coalesced epilogue: idx (float + int) and new_p from LDS
  #pragma unroll
  for (int k = 0; k < MQ / FPS_T; ++k) {
    int j = k * FPS_T + t;
    int wi = win[j];
    out_idxf[b*MQ + j] = (float)wi;
    idx_i[b*MQ + j] = wi;
    float4 c = sp4[wi];
    float* np_ = &out_newp[(size_t)(b*MQ + j) * 3];
    np_[0] = c.x; np_[1] = c.y; np_[2] = c.z;
  }
}

// ------------------------------------------------------------------
// BP1: fused ball query + conv1/stats1. One wave per query.
// Ball query writes its 32 indices to LDS (and global nidx for p2),
// then the same wave gathers and runs conv1 + per-channel sum/sumsq.
// Ballquery math identical to v7 (rn ops, R2 = f32(0.1*0.1), pad with
// first hit / 0).
// ------------------------------------------------------------------
__global__ __launch_bounds__(256) void bp1_kernel(
    const float* __restrict__ p, const float* __restrict__ newp,
    const float* __restrict__ ft, const float* __restrict__ w1p,
    int* __restrict__ nidx, float* __restrict__ stats1) {
  __shared__ __align__(16) float xbuf[4][KS][68];
  __shared__ float wbs[4][64], wbq[4][64];
  __shared__ int nvbuf[4][KS];
  int wv = threadIdx.x >> 6, lane = threadIdx.x & 63;
  int qid = blockIdx.x * 4 + wv;
  int b = qid >> 11;
  const float* pb = p + (size_t)b * NP * 3;
  float qx = newp[qid*3], qy = newp[qid*3+1], qz = newp[qid*3+2];
  float sq_q = __fadd_rn(__fadd_rn(__fmul_rn(qx,qx), __fmul_rn(qy,qy)), __fmul_rn(qz,qz));
  const float R2 = (float)(0.1 * 0.1);   // 0.009999999776482582f
  int found = 0, first = -1;
  for (int base = 0; base < NP; base += 64) {
    int n = base + lane;
    float x = pb[n*3], y = pb[n*3+1], z = pb[n*3+2];
    float sq_p = __fadd_rn(__fadd_rn(__fmul_rn(x,x), __fmul_rn(y,y)), __fmul_rn(z,z));
    float dot  = __fadd_rn(__fadd_rn(__fmul_rn(qx,x), __fmul_rn(qy,y)), __fmul_rn(qz,z));
    float d2   = __fadd_rn(__fadd_rn(sq_q, sq_p), __fmul_rn(-2.0f, dot));
    bool hit = d2 < R2;
    unsigned long long mask = __ballot(hit);
    if (mask) {
      if (first < 0) first = base + __builtin_ctzll(mask);
      int cnt = __popcll(mask);
      if (found < KS) {
        int rank = __popcll(mask & ((1ull << lane) - 1ull));
        if (hit && found + rank < KS) nvbuf[wv][found + rank] = n;
      }
      found += cnt;
      if (found >= KS) break;
    }
  }
  int fcl = found < KS ? found : KS;
  int padv = first < 0 ? 0 : first;
  if (lane >= fcl && lane < KS) nvbuf[wv][lane] = padv;
  __syncthreads();
  // persist for p2 (coalesced 32-lane write)
  if (lane < KS) nidx[(size_t)qid * KS + lane] = nvbuf[wv][lane];
  // ---- gather x = [dp(3) | fj(64) | 0] ----
  for (int kk = 0; kk < KS; ++kk) {
    int n = nvbuf[wv][kk];
    const float* fr = ft + ((size_t)b * NP + n) * 64;
    xbuf[wv][kk][3 + lane] = fr[lane];
    if (lane < 3) {
      const float* pp = p + ((size_t)b * NP + n) * 3;
      float qc = (lane == 0) ? qx : ((lane == 1) ? qy : qz);
      xbuf[wv][kk][lane] = __fsub_rn(pp[lane], qc);
    }
    if (lane == 3) xbuf[wv][kk][67] = 0.0f;
  }
  __syncthreads();
  // conv1: lane = channel o; preload its w row into regs
  const float4* wr = (const float4*)(w1p + lane * 68);
  float4 wreg[17];
  #pragma unroll
  for (int c4 = 0; c4 < 17; ++c4) wreg[c4] = wr[c4];
  float ss = 0.f, qq = 0.f;
  for (int kk = 0; kk < KS; ++kk) {
    const float4* xr = (const float4*)(&xbuf[wv][kk][0]);
    float acc = 0.f;
    #pragma unroll
    for (int c4 = 0; c4 < 17; ++c4) {
      float4 w = wreg[c4]; float4 x = xr[c4];
      acc += w.x*x.x + w.y*x.y + w.z*x.z + w.w*x.w;
    }
    ss += acc; qq += acc * acc;
  }
  wbs[wv][lane] = ss; wbq[wv][lane] = qq;
  __syncthreads();
  if (threadIdx.x < 64) {
    float s  = wbs[0][threadIdx.x] + wbs[1][threadIdx.x] + wbs[2][threadIdx.x] + wbs[3][threadIdx.x];
    float s2 = wbq[0][threadIdx.x] + wbq[1][threadIdx.x] + wbq[2][threadIdx.x] + wbq[3][threadIdx.x];
    int slice = blockIdx.x & 63;
    atomicAdd(&stats1[(slice*2+0)*64 + threadIdx.x], s);
    atomicAdd(&stats1[(slice*2+1)*64 + threadIdx.x], s2);
  }
}

// ------------------------------------------------------------------
// finalize bn1 stats -> scale/shift
// ------------------------------------------------------------------
__global__ void fin1_kernel(const float* __restrict__ stats1,
                            const float* __restrict__ g, const float* __restrict__ bb,
                            float* __restrict__ sc) {
  int o = threadIdx.x;  // 64
  float s = 0.f, q = 0.f;
  for (int sl = 0; sl < 64; ++sl) { s += stats1[(sl*2+0)*64+o]; q += stats1[(sl*2+1)*64+o]; }
  const float cnt = (float)(BB * MQ * KS);
  float mean = s / cnt;
  float var = q / cnt - mean * mean;
  float rstd = 1.0f / sqrtf(var + 1e-5f);
  float gs = g[o] * rstd;
  sc[o] = gs;
  sc[64+o] = bb[o] - mean * gs;
}

__global__ void fin2_kernel(const float* __restrict__ stats2,
                            const float* __restrict__ g, const float* __restrict__ bb,
                            float* __restrict__ sc) {
  int o = threadIdx.x;  // 128
  float s = 0.f, q = 0.f;
  for (int sl = 0; sl < 64; ++sl) { s += stats2[(sl*2+0)*128+o]; q += stats2[(sl*2+1)*128+o]; }
  const float cnt = (float)(BB * MQ * KS);
  float mean = s / cnt;
  float var = q / cnt - mean * mean;
  float rstd = 1.0f / sqrtf(var + 1e-5f);
  float gs = g[o] * rstd;
  sc[o] = gs;
  sc[128+o] = bb[o] - mean * gs;
}

// ------------------------------------------------------------------
// P2: recompute conv1, bn1+relu (h overwrites x rows in LDS), conv2,
// per-channel stats2 + per-query max over K (bn2 commutes with max).
// ------------------------------------------------------------------
__global__ __launch_bounds__(256) void p2_kernel(
    const float* __restrict__ p, const float* __restrict__ newp,
    const float* __restrict__ ft, const int* __restrict__ nidx,
    const float* __restrict__ w1p, const float* __restrict__ w2,
    const float* __restrict__ sc1,
    float* __restrict__ stats2, float* __restrict__ maxy2) {
  __shared__ __align__(16) float xbuf[4][KS][68];
  __shared__ float wbs[4][128], wbq[4][128];
  int wv = threadIdx.x >> 6, lane = threadIdx.x & 63;
  int qid = blockIdx.x * 4 + wv;
  int b = qid >> 11;
  // gather
  int nv = (lane < KS) ? nidx[(size_t)qid * KS + lane] : 0;
  float qx = newp[qid*3], qy = newp[qid*3+1], qz = newp[qid*3+2];
  for (int kk = 0; kk < KS; ++kk) {
    int n = __shfl(nv, kk);
    const float* fr = ft + ((size_t)b * NP + n) * 64;
    xbuf[wv][kk][3 + lane] = fr[lane];
    if (lane < 3) {
      const float* pp = p + ((size_t)b * NP + n) * 3;
      float qc = (lane == 0) ? qx : ((lane == 1) ? qy : qz);
      xbuf[wv][kk][lane] = __fsub_rn(pp[lane], qc);
    }
    if (lane == 3) xbuf[wv][kk][67] = 0.0f;
  }
  __syncthreads();
  // conv1 + bn1 + relu; h[o=lane][kk] written into xbuf[wv][kk][lane]
  {
    const float4* wr = (const float4*)(w1p + lane * 68);
    float4 wreg[17];
    #pragma unroll
    for (int c4 = 0; c4 < 17; ++c4) wreg[c4] = wr[c4];
    float s1v = sc1[lane], t1v = sc1[64 + lane];
    for (int kk = 0; kk < KS; ++kk) {
      const float4* xr = (const float4*)(&xbuf[wv][kk][0]);
      float acc = 0.f;
      #pragma unroll
      for (int c4 = 0; c4 < 17; ++c4) {
        float4 w = wreg[c4]; float4 x = xr[c4];
        acc += w.x*x.x + w.y*x.y + w.z*x.z + w.w*x.w;
      }
      float h = fmaxf(0.0f, fmaf(acc, s1v, t1v));
      xbuf[wv][kk][lane] = h;   // safe: whole row kk consumed by all lanes (lockstep)
    }
  }
  // conv2: lane computes channels lane and lane+64
  const float4* w2a = (const float4*)(w2 + (size_t)lane * 64);
  const float4* w2b = (const float4*)(w2 + (size_t)(lane + 64) * 64);
  float4 wra[16], wrb[16];
  #pragma unroll
  for (int c4 = 0; c4 < 16; ++c4) { wra[c4] = w2a[c4]; wrb[c4] = w2b[c4]; }
  float ss0 = 0.f, qq0 = 0.f, mx0 = -INFINITY;
  float ss1 = 0.f, qq1 = 0.f, mx1 = -INFINITY;
  for (int kk = 0; kk < KS; ++kk) {
    const float4* hr = (const float4*)(&xbuf[wv][kk][0]);
    float a0 = 0.f, a1 = 0.f;
    #pragma unroll
    for (int c4 = 0; c4 < 16; ++c4) {
      float4 h4 = hr[c4];
      float4 wa = wra[c4]; float4 wb = wrb[c4];
      a0 += wa.x*h4.x + wa.y*h4.y + wa.z*h4.z + wa.w*h4.w;
      a1 += wb.x*h4.x + wb.y*h4.y + wb.z*h4.z + wb.w*h4.w;
    }
    ss0 += a0; qq0 += a0*a0; mx0 = fmaxf(mx0, a0);
    ss1 += a1; qq1 += a1*a1; mx1 = fmaxf(mx1, a1);
  }
  maxy2[(size_t)qid * 128 + lane] = mx0;
  maxy2[(size_t)qid * 128 + 64 + lane] = mx1;
  wbs[wv][lane] = ss0; wbs[wv][64+lane] = ss1;
  wbq[wv][lane] = qq0; wbq[wv][64+lane] = qq1;
  __syncthreads();
  if (threadIdx.x < 128) {
    float s  = wbs[0][threadIdx.x] + wbs[1][threadIdx.x] + wbs[2][threadIdx.x] + wbs[3][threadIdx.x];
    float s2 = wbq[0][threadIdx.x] + wbq[1][threadIdx.x] + wbq[2][threadIdx.x] + wbq[3][threadIdx.x];
    int slice = blockIdx.x & 63;
    atomicAdd(&stats2[(slice*2+0)*128 + threadIdx.x], s);
    atomicAdd(&stats2[(slice*2+1)*128 + threadIdx.x], s2);
  }
}

// ------------------------------------------------------------------
// P3: skip conv (w_skip · f[:,idx] + b_skip) + bn2 affine on max + relu
// ------------------------------------------------------------------
__global__ __launch_bounds__(256) void p3_kernel(
    const float* __restrict__ ft, const int* __restrict__ idx_i,
    const float* __restrict__ w_skip, const float* __restrict__ b_skip,
    const float* __restrict__ sc2, const float* __restrict__ maxy2,
    float* __restrict__ outf) {
  int wv = threadIdx.x >> 6, lane = threadIdx.x & 63;
  int qid = blockIdx.x * 4 + wv;
  int b = qid >> 11, m = qid & (MQ - 1);
  int n = idx_i[qid];
  const float4* f4 = (const float4*)(ft + ((size_t)b * NP + n) * 64);
  const float4* wa = (const float4*)(w_skip + (size_t)lane * 64);
  const float4* wb = (const float4*)(w_skip + (size_t)(lane + 64) * 64);
  float a0 = b_skip[lane], a1 = b_skip[lane + 64];
  #pragma unroll
  for (int c4 = 0; c4 < 16; ++c4) {
    float4 x = f4[c4]; float4 u = wa[c4]; float4 v = wb[c4];
    a0 += u.x*x.x + u.y*x.y + u.z*x.z + u.w*x.w;
    a1 += v.x*x.x + v.y*x.y + v.z*x.z + v.w*x.w;
  }
  float v0 = maxy2[(size_t)qid * 128 + lane];
  float v1 = maxy2[(size_t)qid * 128 + 64 + lane];
  float r0 = fmaxf(0.0f, fmaf(v0, sc2[lane],      sc2[128 + lane])      + a0);
  float r1 = fmaxf(0.0f, fmaf(v1, sc2[lane + 64], sc2[128 + lane + 64]) + a1);
  outf[((size_t)b * 128 + lane) * MQ + m] = r0;
  outf[((size_t)b * 128 + lane + 64) * MQ + m] = r1;
}

// ------------------------------------------------------------------
extern "C" void kernel_launch(void* const* d_in, const int* in_sizes, int n_in,
                              void* d_out, int out_size, void* d_ws, size_t ws_size,
                              hipStream_t stream) {
  (void)in_sizes; (void)n_in; (void)out_size; (void)ws_size;
  const float* p   = (const float*)d_in[0];
  const float* f   = (const float*)d_in[1];
  const float* w1  = (const float*)d_in[2];
  const float* g1  = (const float*)d_in[3];
  const float* b1  = (const float*)d_in[4];
  const float* w2  = (const float*)d_in[5];
  const float* g2  = (const float*)d_in[6];
  const float* b2  = (const float*)d_in[7];
  const float* wsk = (const float*)d_in[8];
  const float* bsk = (const float*)d_in[9];
  float* out = (float*)d_out;
  float* wsf = (float*)d_ws;

  float* ft    = wsf + WS_FT;
  int*   nidx  = (int*)(wsf + WS_NIDX);
  int*   idxi  = (int*)(wsf + WS_IDXI);
  float* st1   = wsf + WS_ST1;
  float* st2   = wsf + WS_ST2;
  float* sc1   = wsf + WS_SC1;
  float* sc2   = wsf + WS_SC2;
  float* maxy2 = wsf + WS_MAXY2;
  float* w1p   = wsf + WS_W1P;

  float* out_newp = out;
  float* out_f    = out + BB*MQ*3;

  // zero the atomic stats accumulators (st1+st2 are contiguous)
  (void)hipMemsetAsync(st1, 0, (8192 + 16384) * sizeof(float), stream);

  // fused: blocks 0..3 FPS, 4..515 transpose, 516..524 w1 pad
  fps_fused_kernel<<<4 + 512 + 9, FPS_T, 0, stream>>>(p, out, idxi, f, ft, w1, w1p);
  bp1_kernel<<<BB*MQ/4, 256, 0, stream>>>(p, out_newp, ft, w1p, nidx, st1);
  fin1_kernel<<<1, 64, 0, stream>>>(st1, g1, b1, sc1);
  p2_kernel<<<BB*MQ/4, 256, 0, stream>>>(p, out_newp, ft, nidx, w1p, w2, sc1, st2, maxy2);
  fin2_kernel<<<1, 128, 0, stream>>>(st2, g2, b2, sc2);
  p3_kernel<<<BB*MQ/4, 256, 0, stream>>>(ft, idxi, wsk, bsk, sc2, maxy2, out_f);
}

// Round 5
// 2083.684 us; speedup vs baseline: 1.0873x; 1.0798x over previous
//
#include <hip/hip_runtime.h>
#include <math.h>

#define BB 4
#define NP 8192
#define CF 64
#define MQ 2048
#define KS 32

// ---- workspace layout (float indices) ----
#define WS_FT     0u         // ft: [B][N][64] transposed features (2097152 floats)
#define WS_NIDX   2097152u   // nidx: [B][M][K] int (262144)
#define WS_IDXI   2359296u   // idx int copy: [B][M] (8192)
#define WS_ST1    2367488u   // stats1 slices: [64][2][64] (8192)
#define WS_ST2    2375680u   // stats2 slices: [64][2][128] (16384)
#define WS_SC1    2392064u   // scale/shift bn1: [2][64] (128)
#define WS_SC2    2392192u   // scale/shift bn2: [2][128] (256)
#define WS_MAXY2  2392448u   // maxy2: [B*M][128] (1048576)
#define WS_W1P    3441024u   // padded w1: [64][68] (4352)

typedef float v2f __attribute__((ext_vector_type(2)));

// ------------------------------------------------------------------
// FPS v10: measured ladder (cyc/iter): 256thr=1880 < 512thr=2050 <
// 1024thr=2420 -> per-wave overhead (key+DPP+merge ~95 inst/wave)
// replicates with waves/SIMD while scan issue is constant per SIMD.
// 1 wave/SIMD (256 thr / 32 pts) is optimal. v10 = v7 structure
// + (a) fused transpose/w1pad blocks (run on idle CUs under FPS's
//   ~1.5ms shadow; r4-verified free win),
// + (b) scan trim: track 4-bit winner k via inline-const cndmask
//   instead of materializing nt-512k per slot (saves ~32 v_add/iter);
//   full ~idx reconstructed once after the loop: nt-(k<<9) (chain0,
//   slots (2k)*256+t) / nt-(k<<9)-256 (chain1, (2k+1)*256+t).
//   Same comparisons -> same winner-k -> identical key bits.
// bp1 fusion REVERTED (r4: +66us; ballq wants LDS-free occupancy).
// Selection semantics bit-identical to v7 (passing): packed-f32 scan
// fp contract(off), dual strict-> argmax chains, u64 key
// (f32bits(dmin)<<32)|~idx, DPP wave-max, per-wave slots + dbuf +
// local 4-key merge.
// ------------------------------------------------------------------
#define FPS_T 256
#define FPS_NK 16    // v2f pairs per thread: 32 points/thread

template <int CTRL>
__device__ __forceinline__ unsigned long long dpp_max_step(unsigned long long k) {
  int lo = (int)(unsigned)k;
  int hi = (int)(unsigned)(k >> 32);
  int slo = __builtin_amdgcn_update_dpp(0, lo, CTRL, 0xF, 0xF, true);
  int shi = __builtin_amdgcn_update_dpp(0, hi, CTRL, 0xF, 0xF, true);
  unsigned long long s =
      ((unsigned long long)(unsigned)shi << 32) | (unsigned long long)(unsigned)slo;
  return s > k ? s : k;
}

// LDS pool: fps uses sp4[NP] (128KB) + win[MQ] (8KB) + wkey[2][4];
// transpose uses tile[64][65] (16.6KB).
__global__ __launch_bounds__(256, 1) void fps_fused_kernel(
    const float* __restrict__ p, float* __restrict__ out, int* __restrict__ idx_i,
    const float* __restrict__ f, float* __restrict__ ft,
    const float* __restrict__ w1, float* __restrict__ w1p) {
#pragma clang fp contract(off)
  __shared__ __align__(16) char smem[NP * 16 + MQ * 4 + 2 * 4 * 8];
  int bx = blockIdx.x;
  int t = threadIdx.x;

  if (bx >= 4) {
    if (bx < 4 + 512) {
      // ---- transpose block: tb = bx-4; b = tb>>7, n0 = (tb&127)*64
      float (*tile)[65] = (float (*)[65])smem;
      int tb = bx - 4;
      int b = tb >> 7;
      int n0 = (tb & 127) * 64;
      int cc = t >> 6;   // 0..3
      int nn = t & 63;
      #pragma unroll
      for (int r = 0; r < 16; ++r) {
        int c = cc * 16 + r;
        tile[c][nn] = f[((size_t)b * 64 + c) * NP + n0 + nn];
      }
      __syncthreads();
      #pragma unroll
      for (int r = 0; r < 16; ++r) {
        int nl = cc * 16 + r;
        ft[((size_t)b * NP + n0 + nl) * 64 + nn] = tile[nn][nl];
      }
    } else {
      // ---- w1 pad blocks: 17 x 256 covers 64*68 = 4352
      int i = (bx - 516) * 256 + t;
      if (i < 64 * 68) {
        int o = i / 68, c = i % 68;
        w1p[i] = (c < 67) ? w1[o * 67 + c] : 0.0f;
      }
    }
    return;
  }

  // ---------------- FPS body (blocks 0..3) ----------------
  float4* sp4 = (float4*)smem;                                    // [NP]
  int* win = (int*)(smem + NP * 16);                              // [MQ]
  unsigned long long* wkey = (unsigned long long*)(smem + NP * 16 + MQ * 4); // [2][4]

  int b = bx;
  const float* pb = p + (size_t)b * NP * 3;
  float* out_newp = out;                               // [B][M][3]
  float* out_idxf = out + BB*MQ*3 + (size_t)BB*128*MQ; // [B][M] as float

  v2f px2[FPS_NK], py2[FPS_NK], pz2[FPS_NK];
  float dmn0[FPS_NK], dmn1[FPS_NK];          // even-slot / odd-slot dmin
  #pragma unroll
  for (int k = 0; k < FPS_NK; ++k) {
    int i0 = (2*k) * FPS_T + t;
    int i1 = i0 + FPS_T;
    float x0 = pb[i0*3+0], y0 = pb[i0*3+1], z0 = pb[i0*3+2];
    float x1 = pb[i1*3+0], y1 = pb[i1*3+1], z1 = pb[i1*3+2];
    px2[k] = (v2f){x0, x1}; py2[k] = (v2f){y0, y1}; pz2[k] = (v2f){z0, z1};
    sp4[i0] = make_float4(x0, y0, z0, 0.0f);
    sp4[i1] = make_float4(x1, y1, z1, 0.0f);
    dmn0[k] = INFINITY; dmn1[k] = INFINITY;
  }
  if (t == 0) win[0] = 0;
  __syncthreads();
  float lx = sp4[0].x, ly = sp4[0].y, lz = sp4[0].z;
  unsigned nt = ~(unsigned)t;

  for (int j = 1; j < MQ; ++j) {
#pragma clang fp contract(off)
    v2f l2x = (v2f){lx, lx}, l2y = (v2f){ly, ly}, l2z = (v2f){lz, lz};
    // dual strict-> argmax chains: chain0 = even slots (.x), chain1 = odd (.y)
    // track winner k (inline-const cndmask); reconstruct ~idx after loop.
    float bv0 = -1.0f, bv1 = -1.0f;
    unsigned bk0 = 0u, bk1 = 0u;
    #pragma unroll
    for (int k = 0; k < FPS_NK; ++k) {
      v2f dx = px2[k] - l2x;
      v2f dy = py2[k] - l2y;
      v2f dz = pz2[k] - l2z;
      v2f dd = ((dx*dx) + (dy*dy)) + (dz*dz);
      float m0 = fminf(dmn0[k], dd.x);  dmn0[k] = m0;
      float m1 = fminf(dmn1[k], dd.y);  dmn1[k] = m1;
      bool g0 = m0 > bv0;                 // strict > keeps earliest k
      bv0 = g0 ? m0 : bv0;
      bk0 = g0 ? (unsigned)k : bk0;
      bool g1 = m1 > bv1;
      bv1 = g1 ? m1 : bv1;
      bk1 = g1 ? (unsigned)k : bk1;
    }
    // ~((2*bk0)*256 + t) = nt - (bk0<<9); ~((2*bk1+1)*256 + t) = nt - (bk1<<9) - 256
    unsigned bn0 = nt - (bk0 << 9);
    unsigned bn1 = nt - (bk1 << 9) - 256u;
    unsigned long long k0 =
        ((unsigned long long)__float_as_uint(bv0) << 32) | (unsigned long long)bn0;
    unsigned long long k1 =
        ((unsigned long long)__float_as_uint(bv1) << 32) | (unsigned long long)bn1;
    unsigned long long key = k0 > k1 ? k0 : k1;   // ties: larger ~idx = smaller idx
    // DPP wave-max: result lands in lane 63
    key = dpp_max_step<0x111>(key);  // row_shr:1
    key = dpp_max_step<0x112>(key);  // row_shr:2
    key = dpp_max_step<0x114>(key);  // row_shr:4
    key = dpp_max_step<0x118>(key);  // row_shr:8
    key = dpp_max_step<0x142>(key);  // row_bcast15
    key = dpp_max_step<0x143>(key);  // row_bcast31
    if ((t & 63) == 63) wkey[(j & 1) * 4 + (t >> 6)] = key;   // 4 parallel slot writes
    __syncthreads();                 // single barrier per iteration
    const ulonglong2* wk2 = (const ulonglong2*)(&wkey[(j & 1) * 4]);
    ulonglong2 ka = wk2[0];          // broadcast ds_read_b128
    ulonglong2 kb = wk2[1];
    unsigned long long m0 = ka.x > ka.y ? ka.x : ka.y;
    unsigned long long m1 = kb.x > kb.y ? kb.x : kb.y;
    unsigned long long kw = m0 > m1 ? m0 : m1;
    int wi = (int)(~(unsigned)kw);
    float4 c = sp4[wi];              // one ds_read_b128, same-addr broadcast
    lx = c.x; ly = c.y; lz = c.z;
    if (t == 0) win[j] = wi;
  }

  __syncthreads();
  // bulk coalesced epilogue: idx (float + int) and new_p from LDS
  #pragma unroll
  for (int k = 0; k < MQ / FPS_T; ++k) {
    int j = k * FPS_T + t;
    int wi = win[j];
    out_idxf[b*MQ + j] = (float)wi;
    idx_i[b*MQ + j] = wi;
    float4 c = sp4[wi];
    float* np_ = &out_newp[(size_t)(b*MQ + j) * 3];
    np_[0] = c.x; np_[1] = c.y; np_[2] = c.z;
  }
}

// ------------------------------------------------------------------
// ball query: one wave per query. Mirrors |q|^2+|p|^2-2*dot with rn
// ops; threshold is float( double(0.1)*double(0.1) ).
// ------------------------------------------------------------------
__global__ __launch_bounds__(256) void ballq_kernel(
    const float* __restrict__ p, const float* __restrict__ newp,
    int* __restrict__ nidx) {
  int qid = blockIdx.x * 4 + (threadIdx.x >> 6);   // b*M+m
  int lane = threadIdx.x & 63;
  int b = qid >> 11;
  const float* pb = p + (size_t)b * NP * 3;
  float qx = newp[qid*3], qy = newp[qid*3+1], qz = newp[qid*3+2];
  float sq_q = __fadd_rn(__fadd_rn(__fmul_rn(qx,qx), __fmul_rn(qy,qy)), __fmul_rn(qz,qz));
  const float R2 = (float)(0.1 * 0.1);   // 0.009999999776482582f
  int found = 0, first = -1;
  int* outp = nidx + (size_t)qid * KS;
  for (int base = 0; base < NP; base += 64) {
    int n = base + lane;
    float x = pb[n*3], y = pb[n*3+1], z = pb[n*3+2];
    float sq_p = __fadd_rn(__fadd_rn(__fmul_rn(x,x), __fmul_rn(y,y)), __fmul_rn(z,z));
    float dot  = __fadd_rn(__fadd_rn(__fmul_rn(qx,x), __fmul_rn(qy,y)), __fmul_rn(qz,z));
    float d2   = __fadd_rn(__fadd_rn(sq_q, sq_p), __fmul_rn(-2.0f, dot));
    bool hit = d2 < R2;
    unsigned long long mask = __ballot(hit);
    if (mask) {
      if (first < 0) first = base + __builtin_ctzll(mask);
      int cnt = __popcll(mask);
      if (found < KS) {
        int rank = __popcll(mask & ((1ull << lane) - 1ull));
        if (hit && found + rank < KS) outp[found + rank] = n;
      }
      found += cnt;
      if (found >= KS) break;
    }
  }
  int fcl = found < KS ? found : KS;
  int padv = first < 0 ? 0 : first;
  if (lane >= fcl && lane < KS) outp[lane] = padv;
}

// ------------------------------------------------------------------
// P1: conv1 over gathered x, accumulate per-channel sum/sumsq.
// One wave per query, lane = output channel.
// ------------------------------------------------------------------
__global__ __launch_bounds__(256) void p1_kernel(
    const float* __restrict__ p, const float* __restrict__ newp,
    const float* __restrict__ ft, const int* __restrict__ nidx,
    const float* __restrict__ w1p, float* __restrict__ stats1) {
  __shared__ __align__(16) float xbuf[4][KS][68];
  __shared__ float wbs[4][64], wbq[4][64];
  int wv = threadIdx.x >> 6, lane = threadIdx.x & 63;
  int qid = blockIdx.x * 4 + wv;
  int b = qid >> 11;
  // gather x = [dp(3) | fj(64) | 0]
  int nv = (lane < KS) ? nidx[(size_t)qid * KS + lane] : 0;
  float qx = newp[qid*3], qy = newp[qid*3+1], qz = newp[qid*3+2];
  for (int kk = 0; kk < KS; ++kk) {
    int n = __shfl(nv, kk);
    const float* fr = ft + ((size_t)b * NP + n) * 64;
    xbuf[wv][kk][3 + lane] = fr[lane];
    if (lane < 3) {
      const float* pp = p + ((size_t)b * NP + n) * 3;
      float qc = (lane == 0) ? qx : ((lane == 1) ? qy : qz);
      xbuf[wv][kk][lane] = __fsub_rn(pp[lane], qc);
    }
    if (lane == 3) xbuf[wv][kk][67] = 0.0f;
  }
  __syncthreads();
  // conv1: lane = channel o; preload its w row into regs
  const float4* wr = (const float4*)(w1p + lane * 68);
  float4 wreg[17];
  #pragma unroll
  for (int c4 = 0; c4 < 17; ++c4) wreg[c4] = wr[c4];
  float ss = 0.f, qq = 0.f;
  for (int kk = 0; kk < KS; ++kk) {
    const float4* xr = (const float4*)(&xbuf[wv][kk][0]);
    float acc = 0.f;
    #pragma unroll
    for (int c4 = 0; c4 < 17; ++c4) {
      float4 w = wreg[c4]; float4 x = xr[c4];
      acc += w.x*x.x + w.y*x.y + w.z*x.z + w.w*x.w;
    }
    ss += acc; qq += acc * acc;
  }
  wbs[wv][lane] = ss; wbq[wv][lane] = qq;
  __syncthreads();
  if (threadIdx.x < 64) {
    float s  = wbs[0][threadIdx.x] + wbs[1][threadIdx.x] + wbs[2][threadIdx.x] + wbs[3][threadIdx.x];
    float s2 = wbq[0][threadIdx.x] + wbq[1][threadIdx.x] + wbq[2][threadIdx.x] + wbq[3][threadIdx.x];
    int slice = blockIdx.x & 63;
    atomicAdd(&stats1[(slice*2+0)*64 + threadIdx.x], s);
    atomicAdd(&stats1[(slice*2+1)*64 + threadIdx.x], s2);
  }
}

// ------------------------------------------------------------------
// finalize bn1 stats -> scale/shift
// ------------------------------------------------------------------
__global__ void fin1_kernel(const float* __restrict__ stats1,
                            const float* __restrict__ g, const float* __restrict__ bb,
                            float* __restrict__ sc) {
  int o = threadIdx.x;  // 64
  float s = 0.f, q = 0.f;
  for (int sl = 0; sl < 64; ++sl) { s += stats1[(sl*2+0)*64+o]; q += stats1[(sl*2+1)*64+o]; }
  const float cnt = (float)(BB * MQ * KS);
  float mean = s / cnt;
  float var = q / cnt - mean * mean;
  float rstd = 1.0f / sqrtf(var + 1e-5f);
  float gs = g[o] * rstd;
  sc[o] = gs;
  sc[64+o] = bb[o] - mean * gs;
}

__global__ void fin2_kernel(const float* __restrict__ stats2,
                            const float* __restrict__ g, const float* __restrict__ bb,
                            float* __restrict__ sc) {
  int o = threadIdx.x;  // 128
  float s = 0.f, q = 0.f;
  for (int sl = 0; sl < 64; ++sl) { s += stats2[(sl*2+0)*128+o]; q += stats2[(sl*2+1)*128+o]; }
  const float cnt = (float)(BB * MQ * KS);
  float mean = s / cnt;
  float var = q / cnt - mean * mean;
  float rstd = 1.0f / sqrtf(var + 1e-5f);
  float gs = g[o] * rstd;
  sc[o] = gs;
  sc[128+o] = bb[o] - mean * gs;
}

// ------------------------------------------------------------------
// P2: recompute conv1, bn1+relu (h overwrites x rows in LDS), conv2,
// per-channel stats2 + per-query max over K (bn2 commutes with max).
// ------------------------------------------------------------------
__global__ __launch_bounds__(256) void p2_kernel(
    const float* __restrict__ p, const float* __restrict__ newp,
    const float* __restrict__ ft, const int* __restrict__ nidx,
    const float* __restrict__ w1p, const float* __restrict__ w2,
    const float* __restrict__ sc1,
    float* __restrict__ stats2, float* __restrict__ maxy2) {
  __shared__ __align__(16) float xbuf[4][KS][68];
  __shared__ float wbs[4][128], wbq[4][128];
  int wv = threadIdx.x >> 6, lane = threadIdx.x & 63;
  int qid = blockIdx.x * 4 + wv;
  int b = qid >> 11;
  // gather
  int nv = (lane < KS) ? nidx[(size_t)qid * KS + lane] : 0;
  float qx = newp[qid*3], qy = newp[qid*3+1], qz = newp[qid*3+2];
  for (int kk = 0; kk < KS; ++kk) {
    int n = __shfl(nv, kk);
    const float* fr = ft + ((size_t)b * NP + n) * 64;
    xbuf[wv][kk][3 + lane] = fr[lane];
    if (lane < 3) {
      const float* pp = p + ((size_t)b * NP + n) * 3;
      float qc = (lane == 0) ? qx : ((lane == 1) ? qy : qz);
      xbuf[wv][kk][lane] = __fsub_rn(pp[lane], qc);
    }
    if (lane == 3) xbuf[wv][kk][67] = 0.0f;
  }
  __syncthreads();
  // conv1 + bn1 + relu; h[o=lane][kk] written into xbuf[wv][kk][lane]
  {
    const float4* wr = (const float4*)(w1p + lane * 68);
    float4 wreg[17];
    #pragma unroll
    for (int c4 = 0; c4 < 17; ++c4) wreg[c4] = wr[c4];
    float s1v = sc1[lane], t1v = sc1[64 + lane];
    for (int kk = 0; kk < KS; ++kk) {
      const float4* xr = (const float4*)(&xbuf[wv][kk][0]);
      float acc = 0.f;
      #pragma unroll
      for (int c4 = 0; c4 < 17; ++c4) {
        float4 w = wreg[c4]; float4 x = xr[c4];
        acc += w.x*x.x + w.y*x.y + w.z*x.z + w.w*x.w;
      }
      float h = fmaxf(0.0f, fmaf(acc, s1v, t1v));
      xbuf[wv][kk][lane] = h;   // safe: whole row kk consumed by all lanes (lockstep)
    }
  }
  // conv2: lane computes channels lane and lane+64
  const float4* w2a = (const float4*)(w2 + (size_t)lane * 64);
  const float4* w2b = (const float4*)(w2 + (size_t)(lane + 64) * 64);
  float4 wra[16], wrb[16];
  #pragma unroll
  for (int c4 = 0; c4 < 16; ++c4) { wra[c4] = w2a[c4]; wrb[c4] = w2b[c4]; }
  float ss0 = 0.f, qq0 = 0.f, mx0 = -INFINITY;
  float ss1 = 0.f, qq1 = 0.f, mx1 = -INFINITY;
  for (int kk = 0; kk < KS; ++kk) {
    const float4* hr = (const float4*)(&xbuf[wv][kk][0]);
    float a0 = 0.f, a1 = 0.f;
    #pragma unroll
    for (int c4 = 0; c4 < 16; ++c4) {
      float4 h4 = hr[c4];
      float4 wa = wra[c4]; float4 wb = wrb[c4];
      a0 += wa.x*h4.x + wa.y*h4.y + wa.z*h4.z + wa.w*h4.w;
      a1 += wb.x*h4.x + wb.y*h4.y + wb.z*h4.z + wb.w*h4.w;
    }
    ss0 += a0; qq0 += a0*a0; mx0 = fmaxf(mx0, a0);
    ss1 += a1; qq1 += a1*a1; mx1 = fmaxf(mx1, a1);
  }
  maxy2[(size_t)qid * 128 + lane] = mx0;
  maxy2[(size_t)qid * 128 + 64 + lane] = mx1;
  wbs[wv][lane] = ss0; wbs[wv][64+lane] = ss1;
  wbq[wv][lane] = qq0; wbq[wv][64+lane] = qq1;
  __syncthreads();
  if (threadIdx.x < 128) {
    float s  = wbs[0][threadIdx.x] + wbs[1][threadIdx.x] + wbs[2][threadIdx.x] + wbs[3][threadIdx.x];
    float s2 = wbq[0][threadIdx.x] + wbq[1][threadIdx.x] + wbq[2][threadIdx.x] + wbq[3][threadIdx.x];
    int slice = blockIdx.x & 63;
    atomicAdd(&stats2[(slice*2+0)*128 + threadIdx.x], s);
    atomicAdd(&stats2[(slice*2+1)*128 + threadIdx.x], s2);
  }
}

// ------------------------------------------------------------------
// P3: skip conv (w_skip · f[:,idx] + b_skip) + bn2 affine on max + relu
// ------------------------------------------------------------------
__global__ __launch_bounds__(256) void p3_kernel(
    const float* __restrict__ ft, const int* __restrict__ idx_i,
    const float* __restrict__ w_skip, const float* __restrict__ b_skip,
    const float* __restrict__ sc2, const float* __restrict__ maxy2,
    float* __restrict__ outf) {
  int wv = threadIdx.x >> 6, lane = threadIdx.x & 63;
  int qid = blockIdx.x * 4 + wv;
  int b = qid >> 11, m = qid & (MQ - 1);
  int n = idx_i[qid];
  const float4* f4 = (const float4*)(ft + ((size_t)b * NP + n) * 64);
  const float4* wa = (const float4*)(w_skip + (size_t)lane * 64);
  const float4* wb = (const float4*)(w_skip + (size_t)(lane + 64) * 64);
  float a0 = b_skip[lane], a1 = b_skip[lane + 64];
  #pragma unroll
  for (int c4 = 0; c4 < 16; ++c4) {
    float4 x = f4[c4]; float4 u = wa[c4]; float4 v = wb[c4];
    a0 += u.x*x.x + u.y*x.y + u.z*x.z + u.w*x.w;
    a1 += v.x*x.x + v.y*x.y + v.z*x.z + v.w*x.w;
  }
  float v0 = maxy2[(size_t)qid * 128 + lane];
  float v1 = maxy2[(size_t)qid * 128 + 64 + lane];
  float r0 = fmaxf(0.0f, fmaf(v0, sc2[lane],      sc2[128 + lane])      + a0);
  float r1 = fmaxf(0.0f, fmaf(v1, sc2[lane + 64], sc2[128 + lane + 64]) + a1);
  outf[((size_t)b * 128 + lane) * MQ + m] = r0;
  outf[((size_t)b * 128 + lane + 64) * MQ + m] = r1;
}

// ------------------------------------------------------------------
extern "C" void kernel_launch(void* const* d_in, const int* in_sizes, int n_in,
                              void* d_out, int out_size, void* d_ws, size_t ws_size,
                              hipStream_t stream) {
  (void)in_sizes; (void)n_in; (void)out_size; (void)ws_size;
  const float* p   = (const float*)d_in[0];
  const float* f   = (const float*)d_in[1];
  const float* w1  = (const float*)d_in[2];
  const float* g1  = (const float*)d_in[3];
  const float* b1  = (const float*)d_in[4];
  const float* w2  = (const float*)d_in[5];
  const float* g2  = (const float*)d_in[6];
  const float* b2  = (const float*)d_in[7];
  const float* wsk = (const float*)d_in[8];
  const float* bsk = (const float*)d_in[9];
  float* out = (float*)d_out;
  float* wsf = (float*)d_ws;

  float* ft    = wsf + WS_FT;
  int*   nidx  = (int*)(wsf + WS_NIDX);
  int*   idxi  = (int*)(wsf + WS_IDXI);
  float* st1   = wsf + WS_ST1;
  float* st2   = wsf + WS_ST2;
  float* sc1   = wsf + WS_SC1;
  float* sc2   = wsf + WS_SC2;
  float* maxy2 = wsf + WS_MAXY2;
  float* w1p   = wsf + WS_W1P;

  float* out_newp = out;
  float* out_f    = out + BB*MQ*3;

  // zero the atomic stats accumulators (st1+st2 are contiguous)
  (void)hipMemsetAsync(st1, 0, (8192 + 16384) * sizeof(float), stream);

  // fused: blocks 0..3 FPS, 4..515 transpose, 516..532 w1 pad
  fps_fused_kernel<<<4 + 512 + 17, FPS_T, 0, stream>>>(p, out, idxi, f, ft, w1, w1p);
  ballq_kernel<<<BB*MQ/4, 256, 0, stream>>>(p, out_newp, nidx);
  p1_kernel<<<BB*MQ/4, 256, 0, stream>>>(p, out_newp, ft, nidx, w1p, st1);
  fin1_kernel<<<1, 64, 0, stream>>>(st1, g1, b1, sc1);
  p2_kernel<<<BB*MQ/4, 256, 0, stream>>>(p, out_newp, ft, nidx, w1p, w2, sc1, st2, maxy2);
  fin2_kernel<<<1, 128, 0, stream>>>(st2, g2, b2, sc2);
  p3_kernel<<<BB*MQ/4, 256, 0, stream>>>(ft, idxi, wsk, bsk, sc2, maxy2, out_f);
}

// Round 6
// 2047.853 us; speedup vs baseline: 1.1063x; 1.0175x over previous
//
#include <hip/hip_runtime.h>
#include <math.h>

#define BB 4
#define NP 8192
#define CF 64
#define MQ 2048
#define KS 32

// ---- workspace layout (float indices) ----
#define WS_FT     0u         // ft: [B][N][64] transposed features (2097152 floats)
#define WS_NIDX   2097152u   // nidx: [B][M][K] int (262144)
#define WS_IDXI   2359296u   // idx int copy: [B][M] (8192)
#define WS_ST1    2367488u   // stats1 slices: [64][2][64] (8192)
#define WS_ST2    2375680u   // stats2 slices: [64][2][128] (16384)
#define WS_SC1    2392064u   // scale/shift bn1: [2][64] (128)
#define WS_SC2    2392192u   // scale/shift bn2: [2][128] (256)
#define WS_MAXY2  2392448u   // maxy2: [B*M][128] (1048576)
#define WS_W1P    3441024u   // padded w1: [64][68] (4352)

typedef float v2f __attribute__((ext_vector_type(2)));

// ------------------------------------------------------------------
// FPS v10 (frozen from r5; ~1618us steady): 256 thr / 32 pts, fused
// transpose (blocks 4..515) + w1 pad (516..532) run on idle CUs under
// FPS's shadow. fps per-iter floor ~1880 cyc = scan issue ~1300 +
// barrier/LDS tail ~580; measured ladder 256thr=1880 < 512=2050 <
// 1024=2420 (per-wave reduce overhead replicates). Micro-variants
// (atomic removal, pk-asm, winner-k trim) all within +-5%: parked.
// ------------------------------------------------------------------
#define FPS_T 256
#define FPS_NK 16    // v2f pairs per thread: 32 points/thread

template <int CTRL>
__device__ __forceinline__ unsigned long long dpp_max_step(unsigned long long k) {
  int lo = (int)(unsigned)k;
  int hi = (int)(unsigned)(k >> 32);
  int slo = __builtin_amdgcn_update_dpp(0, lo, CTRL, 0xF, 0xF, true);
  int shi = __builtin_amdgcn_update_dpp(0, hi, CTRL, 0xF, 0xF, true);
  unsigned long long s =
      ((unsigned long long)(unsigned)shi << 32) | (unsigned long long)(unsigned)slo;
  return s > k ? s : k;
}

__global__ __launch_bounds__(256, 1) void fps_fused_kernel(
    const float* __restrict__ p, float* __restrict__ out, int* __restrict__ idx_i,
    const float* __restrict__ f, float* __restrict__ ft,
    const float* __restrict__ w1, float* __restrict__ w1p) {
#pragma clang fp contract(off)
  __shared__ __align__(16) char smem[NP * 16 + MQ * 4 + 2 * 4 * 8];
  int bx = blockIdx.x;
  int t = threadIdx.x;

  if (bx >= 4) {
    if (bx < 4 + 512) {
      // ---- transpose block: tb = bx-4; b = tb>>7, n0 = (tb&127)*64
      float (*tile)[65] = (float (*)[65])smem;
      int tb = bx - 4;
      int b = tb >> 7;
      int n0 = (tb & 127) * 64;
      int cc = t >> 6;   // 0..3
      int nn = t & 63;
      #pragma unroll
      for (int r = 0; r < 16; ++r) {
        int c = cc * 16 + r;
        tile[c][nn] = f[((size_t)b * 64 + c) * NP + n0 + nn];
      }
      __syncthreads();
      #pragma unroll
      for (int r = 0; r < 16; ++r) {
        int nl = cc * 16 + r;
        ft[((size_t)b * NP + n0 + nl) * 64 + nn] = tile[nn][nl];
      }
    } else {
      // ---- w1 pad blocks: 17 x 256 covers 64*68 = 4352
      int i = (bx - 516) * 256 + t;
      if (i < 64 * 68) {
        int o = i / 68, c = i % 68;
        w1p[i] = (c < 67) ? w1[o * 67 + c] : 0.0f;
      }
    }
    return;
  }

  // ---------------- FPS body (blocks 0..3) ----------------
  float4* sp4 = (float4*)smem;                                    // [NP]
  int* win = (int*)(smem + NP * 16);                              // [MQ]
  unsigned long long* wkey = (unsigned long long*)(smem + NP * 16 + MQ * 4); // [2][4]

  int b = bx;
  const float* pb = p + (size_t)b * NP * 3;
  float* out_newp = out;                               // [B][M][3]
  float* out_idxf = out + BB*MQ*3 + (size_t)BB*128*MQ; // [B][M] as float

  v2f px2[FPS_NK], py2[FPS_NK], pz2[FPS_NK];
  float dmn0[FPS_NK], dmn1[FPS_NK];          // even-slot / odd-slot dmin
  #pragma unroll
  for (int k = 0; k < FPS_NK; ++k) {
    int i0 = (2*k) * FPS_T + t;
    int i1 = i0 + FPS_T;
    float x0 = pb[i0*3+0], y0 = pb[i0*3+1], z0 = pb[i0*3+2];
    float x1 = pb[i1*3+0], y1 = pb[i1*3+1], z1 = pb[i1*3+2];
    px2[k] = (v2f){x0, x1}; py2[k] = (v2f){y0, y1}; pz2[k] = (v2f){z0, z1};
    sp4[i0] = make_float4(x0, y0, z0, 0.0f);
    sp4[i1] = make_float4(x1, y1, z1, 0.0f);
    dmn0[k] = INFINITY; dmn1[k] = INFINITY;
  }
  if (t == 0) win[0] = 0;
  __syncthreads();
  float lx = sp4[0].x, ly = sp4[0].y, lz = sp4[0].z;
  unsigned nt = ~(unsigned)t;

  for (int j = 1; j < MQ; ++j) {
#pragma clang fp contract(off)
    v2f l2x = (v2f){lx, lx}, l2y = (v2f){ly, ly}, l2z = (v2f){lz, lz};
    // dual strict-> argmax chains: chain0 = even slots (.x), chain1 = odd (.y)
    float bv0 = -1.0f, bv1 = -1.0f;
    unsigned bk0 = 0u, bk1 = 0u;
    #pragma unroll
    for (int k = 0; k < FPS_NK; ++k) {
      v2f dx = px2[k] - l2x;
      v2f dy = py2[k] - l2y;
      v2f dz = pz2[k] - l2z;
      v2f dd = ((dx*dx) + (dy*dy)) + (dz*dz);
      float m0 = fminf(dmn0[k], dd.x);  dmn0[k] = m0;
      float m1 = fminf(dmn1[k], dd.y);  dmn1[k] = m1;
      bool g0 = m0 > bv0;                 // strict > keeps earliest k
      bv0 = g0 ? m0 : bv0;
      bk0 = g0 ? (unsigned)k : bk0;
      bool g1 = m1 > bv1;
      bv1 = g1 ? m1 : bv1;
      bk1 = g1 ? (unsigned)k : bk1;
    }
    // ~((2*bk0)*256 + t) = nt - (bk0<<9); ~((2*bk1+1)*256 + t) = nt - (bk1<<9) - 256
    unsigned bn0 = nt - (bk0 << 9);
    unsigned bn1 = nt - (bk1 << 9) - 256u;
    unsigned long long k0 =
        ((unsigned long long)__float_as_uint(bv0) << 32) | (unsigned long long)bn0;
    unsigned long long k1 =
        ((unsigned long long)__float_as_uint(bv1) << 32) | (unsigned long long)bn1;
    unsigned long long key = k0 > k1 ? k0 : k1;   // ties: larger ~idx = smaller idx
    // DPP wave-max: result lands in lane 63
    key = dpp_max_step<0x111>(key);  // row_shr:1
    key = dpp_max_step<0x112>(key);  // row_shr:2
    key = dpp_max_step<0x114>(key);  // row_shr:4
    key = dpp_max_step<0x118>(key);  // row_shr:8
    key = dpp_max_step<0x142>(key);  // row_bcast15
    key = dpp_max_step<0x143>(key);  // row_bcast31
    if ((t & 63) == 63) wkey[(j & 1) * 4 + (t >> 6)] = key;   // 4 parallel slot writes
    __syncthreads();                 // single barrier per iteration
    const ulonglong2* wk2 = (const ulonglong2*)(&wkey[(j & 1) * 4]);
    ulonglong2 ka = wk2[0];          // broadcast ds_read_b128
    ulonglong2 kb = wk2[1];
    unsigned long long m0 = ka.x > ka.y ? ka.x : ka.y;
    unsigned long long m1 = kb.x > kb.y ? kb.x : kb.y;
    unsigned long long kw = m0 > m1 ? m0 : m1;
    int wi = (int)(~(unsigned)kw);
    float4 c = sp4[wi];              // one ds_read_b128, same-addr broadcast
    lx = c.x; ly = c.y; lz = c.z;
    if (t == 0) win[j] = wi;
  }

  __syncthreads();
  // bulk coalesced epilogue: idx (float + int) and new_p from LDS
  #pragma unroll
  for (int k = 0; k < MQ / FPS_T; ++k) {
    int j = k * FPS_T + t;
    int wi = win[j];
    out_idxf[b*MQ + j] = (float)wi;
    idx_i[b*MQ + j] = wi;
    float4 c = sp4[wi];
    float* np_ = &out_newp[(size_t)(b*MQ + j) * 3];
    np_[0] = c.x; np_[1] = c.y; np_[2] = c.z;
  }
}

// ------------------------------------------------------------------
// ball query: one wave per query. Mirrors |q|^2+|p|^2-2*dot with rn
// ops; threshold is float( double(0.1)*double(0.1) ).
// ------------------------------------------------------------------
__global__ __launch_bounds__(256) void ballq_kernel(
    const float* __restrict__ p, const float* __restrict__ newp,
    int* __restrict__ nidx) {
  int qid = blockIdx.x * 4 + (threadIdx.x >> 6);   // b*M+m
  int lane = threadIdx.x & 63;
  int b = qid >> 11;
  const float* pb = p + (size_t)b * NP * 3;
  float qx = newp[qid*3], qy = newp[qid*3+1], qz = newp[qid*3+2];
  float sq_q = __fadd_rn(__fadd_rn(__fmul_rn(qx,qx), __fmul_rn(qy,qy)), __fmul_rn(qz,qz));
  const float R2 = (float)(0.1 * 0.1);   // 0.009999999776482582f
  int found = 0, first = -1;
  int* outp = nidx + (size_t)qid * KS;
  for (int base = 0; base < NP; base += 64) {
    int n = base + lane;
    float x = pb[n*3], y = pb[n*3+1], z = pb[n*3+2];
    float sq_p = __fadd_rn(__fadd_rn(__fmul_rn(x,x), __fmul_rn(y,y)), __fmul_rn(z,z));
    float dot  = __fadd_rn(__fadd_rn(__fmul_rn(qx,x), __fmul_rn(qy,y)), __fmul_rn(qz,z));
    float d2   = __fadd_rn(__fadd_rn(sq_q, sq_p), __fmul_rn(-2.0f, dot));
    bool hit = d2 < R2;
    unsigned long long mask = __ballot(hit);
    if (mask) {
      if (first < 0) first = base + __builtin_ctzll(mask);
      int cnt = __popcll(mask);
      if (found < KS) {
        int rank = __popcll(mask & ((1ull << lane) - 1ull));
        if (hit && found + rank < KS) outp[found + rank] = n;
      }
      found += cnt;
      if (found >= KS) break;
    }
  }
  int fcl = found < KS ? found : KS;
  int padv = first < 0 ? 0 : first;
  if (lane >= fcl && lane < KS) outp[lane] = padv;
}

// ------------------------------------------------------------------
// P1 v2: conv1 + stats. Gather is now 8-deep register-staged: the r5
// rolled loop serialized each L2 gather (~250cyc) behind its LDS
// write -> ~9600 cyc/wave-query of exposed latency. Staging 8 loads
// (ft value + p row value) into regs before the 8 LDS writes keeps
// 8 in flight (4 batches). Same loads / __fsub_rn / write addresses
// -> bit-identical outputs.
// ------------------------------------------------------------------
__global__ __launch_bounds__(256) void p1_kernel(
    const float* __restrict__ p, const float* __restrict__ newp,
    const float* __restrict__ ft, const int* __restrict__ nidx,
    const float* __restrict__ w1p, float* __restrict__ stats1) {
  __shared__ __align__(16) float xbuf[4][KS][68];
  __shared__ float wbs[4][64], wbq[4][64];
  int wv = threadIdx.x >> 6, lane = threadIdx.x & 63;
  int qid = blockIdx.x * 4 + wv;
  int b = qid >> 11;
  // gather x = [dp(3) | fj(64) | 0], 8-deep staged
  int nv = (lane < KS) ? nidx[(size_t)qid * KS + lane] : 0;
  float qx = newp[qid*3], qy = newp[qid*3+1], qz = newp[qid*3+2];
  float qc = (lane == 0) ? qx : ((lane == 1) ? qy : qz);
  for (int kb = 0; kb < KS; kb += 8) {
    float gf[8], gp[8];
    #pragma unroll
    for (int u = 0; u < 8; ++u) {
      int n = __shfl(nv, kb + u);
      gf[u] = ft[((size_t)b * NP + n) * 64 + lane];
      if (lane < 3) gp[u] = p[((size_t)b * NP + n) * 3 + lane];
    }
    #pragma unroll
    for (int u = 0; u < 8; ++u) {
      int kk = kb + u;
      xbuf[wv][kk][3 + lane] = gf[u];
      if (lane < 3) xbuf[wv][kk][lane] = __fsub_rn(gp[u], qc);
      if (lane == 3) xbuf[wv][kk][67] = 0.0f;
    }
  }
  __syncthreads();
  // conv1: lane = channel o; preload its w row into regs
  const float4* wr = (const float4*)(w1p + lane * 68);
  float4 wreg[17];
  #pragma unroll
  for (int c4 = 0; c4 < 17; ++c4) wreg[c4] = wr[c4];
  float ss = 0.f, qq = 0.f;
  for (int kk = 0; kk < KS; ++kk) {
    const float4* xr = (const float4*)(&xbuf[wv][kk][0]);
    float acc = 0.f;
    #pragma unroll
    for (int c4 = 0; c4 < 17; ++c4) {
      float4 w = wreg[c4]; float4 x = xr[c4];
      acc += w.x*x.x + w.y*x.y + w.z*x.z + w.w*x.w;
    }
    ss += acc; qq += acc * acc;
  }
  wbs[wv][lane] = ss; wbq[wv][lane] = qq;
  __syncthreads();
  if (threadIdx.x < 64) {
    float s  = wbs[0][threadIdx.x] + wbs[1][threadIdx.x] + wbs[2][threadIdx.x] + wbs[3][threadIdx.x];
    float s2 = wbq[0][threadIdx.x] + wbq[1][threadIdx.x] + wbq[2][threadIdx.x] + wbq[3][threadIdx.x];
    int slice = blockIdx.x & 63;
    atomicAdd(&stats1[(slice*2+0)*64 + threadIdx.x], s);
    atomicAdd(&stats1[(slice*2+1)*64 + threadIdx.x], s2);
  }
}

// ------------------------------------------------------------------
// finalize bn1 stats -> scale/shift
// ------------------------------------------------------------------
__global__ void fin1_kernel(const float* __restrict__ stats1,
                            const float* __restrict__ g, const float* __restrict__ bb,
                            float* __restrict__ sc) {
  int o = threadIdx.x;  // 64
  float s = 0.f, q = 0.f;
  for (int sl = 0; sl < 64; ++sl) { s += stats1[(sl*2+0)*64+o]; q += stats1[(sl*2+1)*64+o]; }
  const float cnt = (float)(BB * MQ * KS);
  float mean = s / cnt;
  float var = q / cnt - mean * mean;
  float rstd = 1.0f / sqrtf(var + 1e-5f);
  float gs = g[o] * rstd;
  sc[o] = gs;
  sc[64+o] = bb[o] - mean * gs;
}

__global__ void fin2_kernel(const float* __restrict__ stats2,
                            const float* __restrict__ g, const float* __restrict__ bb,
                            float* __restrict__ sc) {
  int o = threadIdx.x;  // 128
  float s = 0.f, q = 0.f;
  for (int sl = 0; sl < 64; ++sl) { s += stats2[(sl*2+0)*128+o]; q += stats2[(sl*2+1)*128+o]; }
  const float cnt = (float)(BB * MQ * KS);
  float mean = s / cnt;
  float var = q / cnt - mean * mean;
  float rstd = 1.0f / sqrtf(var + 1e-5f);
  float gs = g[o] * rstd;
  sc[o] = gs;
  sc[128+o] = bb[o] - mean * gs;
}

// ------------------------------------------------------------------
// P2 v2: same 8-deep staged gather; conv1+bn1+relu, conv2, stats2 +
// per-query max (bn2 commutes with max). Conv phases unchanged.
// ------------------------------------------------------------------
__global__ __launch_bounds__(256) void p2_kernel(
    const float* __restrict__ p, const float* __restrict__ newp,
    const float* __restrict__ ft, const int* __restrict__ nidx,
    const float* __restrict__ w1p, const float* __restrict__ w2,
    const float* __restrict__ sc1,
    float* __restrict__ stats2, float* __restrict__ maxy2) {
  __shared__ __align__(16) float xbuf[4][KS][68];
  __shared__ float wbs[4][128], wbq[4][128];
  int wv = threadIdx.x >> 6, lane = threadIdx.x & 63;
  int qid = blockIdx.x * 4 + wv;
  int b = qid >> 11;
  // gather (8-deep staged)
  int nv = (lane < KS) ? nidx[(size_t)qid * KS + lane] : 0;
  float qx = newp[qid*3], qy = newp[qid*3+1], qz = newp[qid*3+2];
  float qc = (lane == 0) ? qx : ((lane == 1) ? qy : qz);
  for (int kb = 0; kb < KS; kb += 8) {
    float gf[8], gp[8];
    #pragma unroll
    for (int u = 0; u < 8; ++u) {
      int n = __shfl(nv, kb + u);
      gf[u] = ft[((size_t)b * NP + n) * 64 + lane];
      if (lane < 3) gp[u] = p[((size_t)b * NP + n) * 3 + lane];
    }
    #pragma unroll
    for (int u = 0; u < 8; ++u) {
      int kk = kb + u;
      xbuf[wv][kk][3 + lane] = gf[u];
      if (lane < 3) xbuf[wv][kk][lane] = __fsub_rn(gp[u], qc);
      if (lane == 3) xbuf[wv][kk][67] = 0.0f;
    }
  }
  __syncthreads();
  // conv1 + bn1 + relu; h[o=lane][kk] written into xbuf[wv][kk][lane]
  {
    const float4* wr = (const float4*)(w1p + lane * 68);
    float4 wreg[17];
    #pragma unroll
    for (int c4 = 0; c4 < 17; ++c4) wreg[c4] = wr[c4];
    float s1v = sc1[lane], t1v = sc1[64 + lane];
    for (int kk = 0; kk < KS; ++kk) {
      const float4* xr = (const float4*)(&xbuf[wv][kk][0]);
      float acc = 0.f;
      #pragma unroll
      for (int c4 = 0; c4 < 17; ++c4) {
        float4 w = wreg[c4]; float4 x = xr[c4];
        acc += w.x*x.x + w.y*x.y + w.z*x.z + w.w*x.w;
      }
      float h = fmaxf(0.0f, fmaf(acc, s1v, t1v));
      xbuf[wv][kk][lane] = h;   // safe: whole row kk consumed by all lanes (lockstep)
    }
  }
  // conv2: lane computes channels lane and lane+64
  const float4* w2a = (const float4*)(w2 + (size_t)lane * 64);
  const float4* w2b = (const float4*)(w2 + (size_t)(lane + 64) * 64);
  float4 wra[16], wrb[16];
  #pragma unroll
  for (int c4 = 0; c4 < 16; ++c4) { wra[c4] = w2a[c4]; wrb[c4] = w2b[c4]; }
  float ss0 = 0.f, qq0 = 0.f, mx0 = -INFINITY;
  float ss1 = 0.f, qq1 = 0.f, mx1 = -INFINITY;
  for (int kk = 0; kk < KS; ++kk) {
    const float4* hr = (const float4*)(&xbuf[wv][kk][0]);
    float a0 = 0.f, a1 = 0.f;
    #pragma unroll
    for (int c4 = 0; c4 < 16; ++c4) {
      float4 h4 = hr[c4];
      float4 wa = wra[c4]; float4 wb = wrb[c4];
      a0 += wa.x*h4.x + wa.y*h4.y + wa.z*h4.z + wa.w*h4.w;
      a1 += wb.x*h4.x + wb.y*h4.y + wb.z*h4.z + wb.w*h4.w;
    }
    ss0 += a0; qq0 += a0*a0; mx0 = fmaxf(mx0, a0);
    ss1 += a1; qq1 += a1*a1; mx1 = fmaxf(mx1, a1);
  }
  maxy2[(size_t)qid * 128 + lane] = mx0;
  maxy2[(size_t)qid * 128 + 64 + lane] = mx1;
  wbs[wv][lane] = ss0; wbs[wv][64+lane] = ss1;
  wbq[wv][lane] = qq0; wbq[wv][64+lane] = qq1;
  __syncthreads();
  if (threadIdx.x < 128) {
    float s  = wbs[0][threadIdx.x] + wbs[1][threadIdx.x] + wbs[2][threadIdx.x] + wbs[3][threadIdx.x];
    float s2 = wbq[0][threadIdx.x] + wbq[1][threadIdx.x] + wbq[2][threadIdx.x] + wbq[3][threadIdx.x];
    int slice = blockIdx.x & 63;
    atomicAdd(&stats2[(slice*2+0)*128 + threadIdx.x], s);
    atomicAdd(&stats2[(slice*2+1)*128 + threadIdx.x], s2);
  }
}

// ------------------------------------------------------------------
// P3: skip conv (w_skip · f[:,idx] + b_skip) + bn2 affine on max + relu
// ------------------------------------------------------------------
__global__ __launch_bounds__(256) void p3_kernel(
    const float* __restrict__ ft, const int* __restrict__ idx_i,
    const float* __restrict__ w_skip, const float* __restrict__ b_skip,
    const float* __restrict__ sc2, const float* __restrict__ maxy2,
    float* __restrict__ outf) {
  int wv = threadIdx.x >> 6, lane = threadIdx.x & 63;
  int qid = blockIdx.x * 4 + wv;
  int b = qid >> 11, m = qid & (MQ - 1);
  int n = idx_i[qid];
  const float4* f4 = (const float4*)(ft + ((size_t)b * NP + n) * 64);
  const float4* wa = (const float4*)(w_skip + (size_t)lane * 64);
  const float4* wb = (const float4*)(w_skip + (size_t)(lane + 64) * 64);
  float a0 = b_skip[lane], a1 = b_skip[lane + 64];
  #pragma unroll
  for (int c4 = 0; c4 < 16; ++c4) {
    float4 x = f4[c4]; float4 u = wa[c4]; float4 v = wb[c4];
    a0 += u.x*x.x + u.y*x.y + u.z*x.z + u.w*x.w;
    a1 += v.x*x.x + v.y*x.y + v.z*x.z + v.w*x.w;
  }
  float v0 = maxy2[(size_t)qid * 128 + lane];
  float v1 = maxy2[(size_t)qid * 128 + 64 + lane];
  float r0 = fmaxf(0.0f, fmaf(v0, sc2[lane],      sc2[128 + lane])      + a0);
  float r1 = fmaxf(0.0f, fmaf(v1, sc2[lane + 64], sc2[128 + lane + 64]) + a1);
  outf[((size_t)b * 128 + lane) * MQ + m] = r0;
  outf[((size_t)b * 128 + lane + 64) * MQ + m] = r1;
}

// ------------------------------------------------------------------
extern "C" void kernel_launch(void* const* d_in, const int* in_sizes, int n_in,
                              void* d_out, int out_size, void* d_ws, size_t ws_size,
                              hipStream_t stream) {
  (void)in_sizes; (void)n_in; (void)out_size; (void)ws_size;
  const float* p   = (const float*)d_in[0];
  const float* f   = (const float*)d_in[1];
  const float* w1  = (const float*)d_in[2];
  const float* g1  = (const float*)d_in[3];
  const float* b1  = (const float*)d_in[4];
  const float* w2  = (const float*)d_in[5];
  const float* g2  = (const float*)d_in[6];
  const float* b2  = (const float*)d_in[7];
  const float* wsk = (const float*)d_in[8];
  const float* bsk = (const float*)d_in[9];
  float* out = (float*)d_out;
  float* wsf = (float*)d_ws;

  float* ft    = wsf + WS_FT;
  int*   nidx  = (int*)(wsf + WS_NIDX);
  int*   idxi  = (int*)(wsf + WS_IDXI);
  float* st1   = wsf + WS_ST1;
  float* st2   = wsf + WS_ST2;
  float* sc1   = wsf + WS_SC1;
  float* sc2   = wsf + WS_SC2;
  float* maxy2 = wsf + WS_MAXY2;
  float* w1p   = wsf + WS_W1P;

  float* out_newp = out;
  float* out_f    = out + BB*MQ*3;

  // zero the atomic stats accumulators (st1+st2 are contiguous)
  (void)hipMemsetAsync(st1, 0, (8192 + 16384) * sizeof(float), stream);

  // fused: blocks 0..3 FPS, 4..515 transpose, 516..532 w1 pad
  fps_fused_kernel<<<4 + 512 + 17, FPS_T, 0, stream>>>(p, out, idxi, f, ft, w1, w1p);
  ballq_kernel<<<BB*MQ/4, 256, 0, stream>>>(p, out_newp, nidx);
  p1_kernel<<<BB*MQ/4, 256, 0, stream>>>(p, out_newp, ft, nidx, w1p, st1);
  fin1_kernel<<<1, 64, 0, stream>>>(st1, g1, b1, sc1);
  p2_kernel<<<BB*MQ/4, 256, 0, stream>>>(p, out_newp, ft, nidx, w1p, w2, sc1, st2, maxy2);
  fin2_kernel<<<1, 128, 0, stream>>>(st2, g2, b2, sc2);
  p3_kernel<<<BB*MQ/4, 256, 0, stream>>>(ft, idxi, wsk, bsk, sc2, maxy2, out_f);
}

// Round 7
// 1896.762 us; speedup vs baseline: 1.1944x; 1.0797x over previous
//
#include <hip/hip_runtime.h>
#include <math.h>

#define BB 4
#define NP 8192
#define CF 64
#define MQ 2048
#define KS 32

// ---- workspace layout (float indices) ----
#define WS_G      0u         // g: [B][N][64] = W1_f·f_n + W1_dp·p_n (2097152 floats; replaces ft)
#define WS_NIDX   2097152u   // nidx: [B][M][K] int (262144)
#define WS_IDXI   2359296u   // idx int copy: [B][M] (8192)
#define WS_ST1    2367488u   // stats1 slices: [64][2][64] (8192)
#define WS_ST2    2375680u   // stats2 slices: [64][2][128] (16384)
#define WS_SC1    2392064u   // scale/shift bn1: [2][64] (128)
#define WS_SC2    2392192u   // scale/shift bn2: [2][128] (256)
#define WS_MAXY2  2392448u   // maxy2: [B*M][128] (1048576)

typedef float v2f __attribute__((ext_vector_type(2)));

// ------------------------------------------------------------------
// FPS v11 (fps body frozen; ~1620us steady): 256 thr / 32 pts.
// Fused shadow blocks 4..515 now compute g[b][n][o] = sum_c
// w1[o][3+c]*f[b][c][n] + sum_d w1[o][d]*p[b][n][d] for all points
// (conv1's point-only part; conv1(x)[q,k] = g[n] - W_dp*q). This
// replaces the ft transpose entirely: p1/p2 consume g, p3 reads raw
// f columns. g work (143M MAC) runs on the 252 idle CUs under FPS's
// 1.6ms shadow -> free.
// fps floor ~1880 cyc/iter = scan issue ~1300 + barrier/LDS tail
// ~580; ladder 256thr=1880 < 512=2050 < 1024=2420 (per-wave reduce
// overhead replicates). Micro-variants all +-5%: parked.
// ------------------------------------------------------------------
#define FPS_T 256
#define FPS_NK 16    // v2f pairs per thread: 32 points/thread

template <int CTRL>
__device__ __forceinline__ unsigned long long dpp_max_step(unsigned long long k) {
  int lo = (int)(unsigned)k;
  int hi = (int)(unsigned)(k >> 32);
  int slo = __builtin_amdgcn_update_dpp(0, lo, CTRL, 0xF, 0xF, true);
  int shi = __builtin_amdgcn_update_dpp(0, hi, CTRL, 0xF, 0xF, true);
  unsigned long long s =
      ((unsigned long long)(unsigned)shi << 32) | (unsigned long long)(unsigned)slo;
  return s > k ? s : k;
}

__global__ __launch_bounds__(256, 1) void fps_fused_kernel(
    const float* __restrict__ p, float* __restrict__ out, int* __restrict__ idx_i,
    const float* __restrict__ f, float* __restrict__ gout,
    const float* __restrict__ w1) {
#pragma clang fp contract(off)
  __shared__ __align__(16) char smem[NP * 16 + MQ * 4 + 2 * 4 * 8];
  int bx = blockIdx.x;
  int t = threadIdx.x;

  if (bx >= 4) {
    // ---- g block: tb in 0..511; b = tb>>7, n0 = (tb&127)*64 ----
    float (*tile)[65] = (float (*)[65])smem;                  // [64][65] f tile
    float (*wlds)[68] = (float (*)[68])(smem + 16640);        // [64][68] w1 rows
    float* plds = (float*)(smem + 16640 + 17408);             // [192] p coords
    int tb = bx - 4;
    int b = tb >> 7;
    int n0 = (tb & 127) * 64;
    int cc = t >> 6;   // 0..3
    int nn = t & 63;
    #pragma unroll
    for (int r = 0; r < 16; ++r) {
      int c = cc * 16 + r;
      tile[c][nn] = f[((size_t)b * 64 + c) * NP + n0 + nn];
    }
    for (int i = t; i < 64 * 67; i += 256) {
      wlds[i / 67][i % 67] = w1[i];
    }
    if (t < 192) plds[t] = p[((size_t)b * NP + n0) * 3 + t];
    __syncthreads();
    int wv = t >> 6, lane = t & 63;
    float wreg[67];
    #pragma unroll
    for (int c = 0; c < 67; ++c) wreg[c] = wlds[lane][c];
    for (int q = 0; q < 16; ++q) {
      int pt = wv * 16 + q;
      float acc = wreg[0] * plds[pt * 3 + 0];
      acc += wreg[1] * plds[pt * 3 + 1];
      acc += wreg[2] * plds[pt * 3 + 2];
      #pragma unroll
      for (int c = 0; c < 64; ++c) acc += wreg[3 + c] * tile[c][pt];
      gout[((size_t)b * NP + n0 + pt) * 64 + lane] = acc;
    }
    return;
  }

  // ---------------- FPS body (blocks 0..3, frozen) ----------------
  float4* sp4 = (float4*)smem;                                    // [NP]
  int* win = (int*)(smem + NP * 16);                              // [MQ]
  unsigned long long* wkey = (unsigned long long*)(smem + NP * 16 + MQ * 4); // [2][4]

  int b = bx;
  const float* pb = p + (size_t)b * NP * 3;
  float* out_newp = out;                               // [B][M][3]
  float* out_idxf = out + BB*MQ*3 + (size_t)BB*128*MQ; // [B][M] as float

  v2f px2[FPS_NK], py2[FPS_NK], pz2[FPS_NK];
  float dmn0[FPS_NK], dmn1[FPS_NK];          // even-slot / odd-slot dmin
  #pragma unroll
  for (int k = 0; k < FPS_NK; ++k) {
    int i0 = (2*k) * FPS_T + t;
    int i1 = i0 + FPS_T;
    float x0 = pb[i0*3+0], y0 = pb[i0*3+1], z0 = pb[i0*3+2];
    float x1 = pb[i1*3+0], y1 = pb[i1*3+1], z1 = pb[i1*3+2];
    px2[k] = (v2f){x0, x1}; py2[k] = (v2f){y0, y1}; pz2[k] = (v2f){z0, z1};
    sp4[i0] = make_float4(x0, y0, z0, 0.0f);
    sp4[i1] = make_float4(x1, y1, z1, 0.0f);
    dmn0[k] = INFINITY; dmn1[k] = INFINITY;
  }
  if (t == 0) win[0] = 0;
  __syncthreads();
  float lx = sp4[0].x, ly = sp4[0].y, lz = sp4[0].z;
  unsigned nt = ~(unsigned)t;

  for (int j = 1; j < MQ; ++j) {
#pragma clang fp contract(off)
    v2f l2x = (v2f){lx, lx}, l2y = (v2f){ly, ly}, l2z = (v2f){lz, lz};
    // dual strict-> argmax chains: chain0 = even slots (.x), chain1 = odd (.y)
    float bv0 = -1.0f, bv1 = -1.0f;
    unsigned bk0 = 0u, bk1 = 0u;
    #pragma unroll
    for (int k = 0; k < FPS_NK; ++k) {
      v2f dx = px2[k] - l2x;
      v2f dy = py2[k] - l2y;
      v2f dz = pz2[k] - l2z;
      v2f dd = ((dx*dx) + (dy*dy)) + (dz*dz);
      float m0 = fminf(dmn0[k], dd.x);  dmn0[k] = m0;
      float m1 = fminf(dmn1[k], dd.y);  dmn1[k] = m1;
      bool g0 = m0 > bv0;                 // strict > keeps earliest k
      bv0 = g0 ? m0 : bv0;
      bk0 = g0 ? (unsigned)k : bk0;
      bool g1 = m1 > bv1;
      bv1 = g1 ? m1 : bv1;
      bk1 = g1 ? (unsigned)k : bk1;
    }
    // ~((2*bk0)*256 + t) = nt - (bk0<<9); ~((2*bk1+1)*256 + t) = nt - (bk1<<9) - 256
    unsigned bn0 = nt - (bk0 << 9);
    unsigned bn1 = nt - (bk1 << 9) - 256u;
    unsigned long long k0 =
        ((unsigned long long)__float_as_uint(bv0) << 32) | (unsigned long long)bn0;
    unsigned long long k1 =
        ((unsigned long long)__float_as_uint(bv1) << 32) | (unsigned long long)bn1;
    unsigned long long key = k0 > k1 ? k0 : k1;   // ties: larger ~idx = smaller idx
    // DPP wave-max: result lands in lane 63
    key = dpp_max_step<0x111>(key);  // row_shr:1
    key = dpp_max_step<0x112>(key);  // row_shr:2
    key = dpp_max_step<0x114>(key);  // row_shr:4
    key = dpp_max_step<0x118>(key);  // row_shr:8
    key = dpp_max_step<0x142>(key);  // row_bcast15
    key = dpp_max_step<0x143>(key);  // row_bcast31
    if ((t & 63) == 63) wkey[(j & 1) * 4 + (t >> 6)] = key;   // 4 parallel slot writes
    __syncthreads();                 // single barrier per iteration
    const ulonglong2* wk2 = (const ulonglong2*)(&wkey[(j & 1) * 4]);
    ulonglong2 ka = wk2[0];          // broadcast ds_read_b128
    ulonglong2 kb = wk2[1];
    unsigned long long m0 = ka.x > ka.y ? ka.x : ka.y;
    unsigned long long m1 = kb.x > kb.y ? kb.x : kb.y;
    unsigned long long kw = m0 > m1 ? m0 : m1;
    int wi = (int)(~(unsigned)kw);
    float4 c = sp4[wi];              // one ds_read_b128, same-addr broadcast
    lx = c.x; ly = c.y; lz = c.z;
    if (t == 0) win[j] = wi;
  }

  __syncthreads();
  // bulk coalesced epilogue: idx (float + int) and new_p from LDS
  #pragma unroll
  for (int k = 0; k < MQ / FPS_T; ++k) {
    int j = k * FPS_T + t;
    int wi = win[j];
    out_idxf[b*MQ + j] = (float)wi;
    idx_i[b*MQ + j] = wi;
    float4 c = sp4[wi];
    float* np_ = &out_newp[(size_t)(b*MQ + j) * 3];
    np_[0] = c.x; np_[1] = c.y; np_[2] = c.z;
  }
}

// ------------------------------------------------------------------
// ball query: one wave per query. Mirrors |q|^2+|p|^2-2*dot with rn
// ops; threshold is float( double(0.1)*double(0.1) ).
// ------------------------------------------------------------------
__global__ __launch_bounds__(256) void ballq_kernel(
    const float* __restrict__ p, const float* __restrict__ newp,
    int* __restrict__ nidx) {
  int qid = blockIdx.x * 4 + (threadIdx.x >> 6);   // b*M+m
  int lane = threadIdx.x & 63;
  int b = qid >> 11;
  const float* pb = p + (size_t)b * NP * 3;
  float qx = newp[qid*3], qy = newp[qid*3+1], qz = newp[qid*3+2];
  float sq_q = __fadd_rn(__fadd_rn(__fmul_rn(qx,qx), __fmul_rn(qy,qy)), __fmul_rn(qz,qz));
  const float R2 = (float)(0.1 * 0.1);   // 0.009999999776482582f
  int found = 0, first = -1;
  int* outp = nidx + (size_t)qid * KS;
  for (int base = 0; base < NP; base += 64) {
    int n = base + lane;
    float x = pb[n*3], y = pb[n*3+1], z = pb[n*3+2];
    float sq_p = __fadd_rn(__fadd_rn(__fmul_rn(x,x), __fmul_rn(y,y)), __fmul_rn(z,z));
    float dot  = __fadd_rn(__fadd_rn(__fmul_rn(qx,x), __fmul_rn(qy,y)), __fmul_rn(qz,z));
    float d2   = __fadd_rn(__fadd_rn(sq_q, sq_p), __fmul_rn(-2.0f, dot));
    bool hit = d2 < R2;
    unsigned long long mask = __ballot(hit);
    if (mask) {
      if (first < 0) first = base + __builtin_ctzll(mask);
      int cnt = __popcll(mask);
      if (found < KS) {
        int rank = __popcll(mask & ((1ull << lane) - 1ull));
        if (hit && found + rank < KS) outp[found + rank] = n;
      }
      found += cnt;
      if (found >= KS) break;
    }
  }
  int fcl = found < KS ? found : KS;
  int padv = first < 0 ? 0 : first;
  if (lane >= fcl && lane < KS) outp[lane] = padv;
}

// ------------------------------------------------------------------
// P1 v3: conv1 via g-gather. acc[q,k,o] = g[n][o] - hq[o] where
// hq = W_dp·q (3 FMAs/lane). No xbuf, no w-regs, no dp gather:
// 32 coalesced 256B row loads (8-deep staged) + sub + stats.
// ------------------------------------------------------------------
__global__ __launch_bounds__(256) void p1_kernel(
    const float* __restrict__ g, const float* __restrict__ newp,
    const float* __restrict__ w1, const int* __restrict__ nidx,
    float* __restrict__ stats1) {
  __shared__ float wbs[4][64], wbq[4][64];
  int wv = threadIdx.x >> 6, lane = threadIdx.x & 63;
  int qid = blockIdx.x * 4 + wv;
  int b = qid >> 11;
  int nv = (lane < KS) ? nidx[(size_t)qid * KS + lane] : 0;
  float qx = newp[qid*3], qy = newp[qid*3+1], qz = newp[qid*3+2];
  float w0 = w1[lane*67+0], w1c = w1[lane*67+1], w2c = w1[lane*67+2];
  float hq = w0*qx + w1c*qy + w2c*qz;
  float ss = 0.f, qq = 0.f;
  for (int kb = 0; kb < KS; kb += 8) {
    float gv[8];
    #pragma unroll
    for (int u = 0; u < 8; ++u) {
      int n = __shfl(nv, kb + u);
      gv[u] = g[((size_t)b * NP + n) * 64 + lane];
    }
    #pragma unroll
    for (int u = 0; u < 8; ++u) {
      float a = gv[u] - hq;
      ss += a; qq += a * a;
    }
  }
  wbs[wv][lane] = ss; wbq[wv][lane] = qq;
  __syncthreads();
  if (threadIdx.x < 64) {
    float s  = wbs[0][threadIdx.x] + wbs[1][threadIdx.x] + wbs[2][threadIdx.x] + wbs[3][threadIdx.x];
    float s2 = wbq[0][threadIdx.x] + wbq[1][threadIdx.x] + wbq[2][threadIdx.x] + wbq[3][threadIdx.x];
    int slice = blockIdx.x & 63;
    atomicAdd(&stats1[(slice*2+0)*64 + threadIdx.x], s);
    atomicAdd(&stats1[(slice*2+1)*64 + threadIdx.x], s2);
  }
}

// ------------------------------------------------------------------
// finalize bn stats -> scale/shift
// ------------------------------------------------------------------
__global__ void fin1_kernel(const float* __restrict__ stats1,
                            const float* __restrict__ g, const float* __restrict__ bb,
                            float* __restrict__ sc) {
  int o = threadIdx.x;  // 64
  float s = 0.f, q = 0.f;
  for (int sl = 0; sl < 64; ++sl) { s += stats1[(sl*2+0)*64+o]; q += stats1[(sl*2+1)*64+o]; }
  const float cnt = (float)(BB * MQ * KS);
  float mean = s / cnt;
  float var = q / cnt - mean * mean;
  float rstd = 1.0f / sqrtf(var + 1e-5f);
  float gs = g[o] * rstd;
  sc[o] = gs;
  sc[64+o] = bb[o] - mean * gs;
}

__global__ void fin2_kernel(const float* __restrict__ stats2,
                            const float* __restrict__ g, const float* __restrict__ bb,
                            float* __restrict__ sc) {
  int o = threadIdx.x;  // 128
  float s = 0.f, q = 0.f;
  for (int sl = 0; sl < 64; ++sl) { s += stats2[(sl*2+0)*128+o]; q += stats2[(sl*2+1)*128+o]; }
  const float cnt = (float)(BB * MQ * KS);
  float mean = s / cnt;
  float var = q / cnt - mean * mean;
  float rstd = 1.0f / sqrtf(var + 1e-5f);
  float gs = g[o] * rstd;
  sc[o] = gs;
  sc[128+o] = bb[o] - mean * gs;
}

// ------------------------------------------------------------------
// P2 v3: h = relu(bn1(g[n]-hq)) built straight into LDS (conv1 FMA
// loop deleted), then conv2 + stats2 + per-query max (bn2 commutes
// with max). conv2 phase unchanged from passing version.
// ------------------------------------------------------------------
__global__ __launch_bounds__(256) void p2_kernel(
    const float* __restrict__ g, const float* __restrict__ newp,
    const float* __restrict__ w1, const float* __restrict__ w2,
    const int* __restrict__ nidx, const float* __restrict__ sc1,
    float* __restrict__ stats2, float* __restrict__ maxy2) {
  __shared__ __align__(16) float xbuf[4][KS][68];
  __shared__ float wbs[4][128], wbq[4][128];
  int wv = threadIdx.x >> 6, lane = threadIdx.x & 63;
  int qid = blockIdx.x * 4 + wv;
  int b = qid >> 11;
  int nv = (lane < KS) ? nidx[(size_t)qid * KS + lane] : 0;
  float qx = newp[qid*3], qy = newp[qid*3+1], qz = newp[qid*3+2];
  float w0 = w1[lane*67+0], w1c = w1[lane*67+1], w2c = w1[lane*67+2];
  float hq = w0*qx + w1c*qy + w2c*qz;
  float s1v = sc1[lane], t1v = sc1[64 + lane];
  for (int kb = 0; kb < KS; kb += 8) {
    float gv[8];
    #pragma unroll
    for (int u = 0; u < 8; ++u) {
      int n = __shfl(nv, kb + u);
      gv[u] = g[((size_t)b * NP + n) * 64 + lane];
    }
    #pragma unroll
    for (int u = 0; u < 8; ++u) {
      float a = gv[u] - hq;
      float h = fmaxf(0.0f, fmaf(a, s1v, t1v));
      xbuf[wv][kb + u][lane] = h;
    }
  }
  __syncthreads();
  // conv2: lane computes channels lane and lane+64
  const float4* w2a = (const float4*)(w2 + (size_t)lane * 64);
  const float4* w2b = (const float4*)(w2 + (size_t)(lane + 64) * 64);
  float4 wra[16], wrb[16];
  #pragma unroll
  for (int c4 = 0; c4 < 16; ++c4) { wra[c4] = w2a[c4]; wrb[c4] = w2b[c4]; }
  float ss0 = 0.f, qq0 = 0.f, mx0 = -INFINITY;
  float ss1 = 0.f, qq1 = 0.f, mx1 = -INFINITY;
  for (int kk = 0; kk < KS; ++kk) {
    const float4* hr = (const float4*)(&xbuf[wv][kk][0]);
    float a0 = 0.f, a1 = 0.f;
    #pragma unroll
    for (int c4 = 0; c4 < 16; ++c4) {
      float4 h4 = hr[c4];
      float4 wa = wra[c4]; float4 wb = wrb[c4];
      a0 += wa.x*h4.x + wa.y*h4.y + wa.z*h4.z + wa.w*h4.w;
      a1 += wb.x*h4.x + wb.y*h4.y + wb.z*h4.z + wb.w*h4.w;
    }
    ss0 += a0; qq0 += a0*a0; mx0 = fmaxf(mx0, a0);
    ss1 += a1; qq1 += a1*a1; mx1 = fmaxf(mx1, a1);
  }
  maxy2[(size_t)qid * 128 + lane] = mx0;
  maxy2[(size_t)qid * 128 + 64 + lane] = mx1;
  wbs[wv][lane] = ss0; wbs[wv][64+lane] = ss1;
  wbq[wv][lane] = qq0; wbq[wv][64+lane] = qq1;
  __syncthreads();
  if (threadIdx.x < 128) {
    float s  = wbs[0][threadIdx.x] + wbs[1][threadIdx.x] + wbs[2][threadIdx.x] + wbs[3][threadIdx.x];
    float s2 = wbq[0][threadIdx.x] + wbq[1][threadIdx.x] + wbq[2][threadIdx.x] + wbq[3][threadIdx.x];
    int slice = blockIdx.x & 63;
    atomicAdd(&stats2[(slice*2+0)*128 + threadIdx.x], s);
    atomicAdd(&stats2[(slice*2+1)*128 + threadIdx.x], s2);
  }
}

// ------------------------------------------------------------------
// P3 v2: skip conv from RAW f (column gather: one per-lane strided
// load into LDS, then broadcast float4 dot — identical arithmetic
// order to the old ft-row version) + bn2 affine on max + relu.
// ------------------------------------------------------------------
__global__ __launch_bounds__(256) void p3_kernel(
    const float* __restrict__ f, const int* __restrict__ idx_i,
    const float* __restrict__ w_skip, const float* __restrict__ b_skip,
    const float* __restrict__ sc2, const float* __restrict__ maxy2,
    float* __restrict__ outf) {
  __shared__ __align__(16) float flds[4][64];
  int wv = threadIdx.x >> 6, lane = threadIdx.x & 63;
  int qid = blockIdx.x * 4 + wv;
  int b = qid >> 11, m = qid & (MQ - 1);
  int n = idx_i[qid];
  flds[wv][lane] = f[((size_t)b * 64 + lane) * NP + n];   // column gather
  const float4* f4 = (const float4*)(&flds[wv][0]);        // same-wave w->r
  const float4* wa = (const float4*)(w_skip + (size_t)lane * 64);
  const float4* wb = (const float4*)(w_skip + (size_t)(lane + 64) * 64);
  float a0 = b_skip[lane], a1 = b_skip[lane + 64];
  #pragma unroll
  for (int c4 = 0; c4 < 16; ++c4) {
    float4 x = f4[c4]; float4 u = wa[c4]; float4 v = wb[c4];
    a0 += u.x*x.x + u.y*x.y + u.z*x.z + u.w*x.w;
    a1 += v.x*x.x + v.y*x.y + v.z*x.z + v.w*x.w;
  }
  float v0 = maxy2[(size_t)qid * 128 + lane];
  float v1 = maxy2[(size_t)qid * 128 + 64 + lane];
  float r0 = fmaxf(0.0f, fmaf(v0, sc2[lane],      sc2[128 + lane])      + a0);
  float r1 = fmaxf(0.0f, fmaf(v1, sc2[lane + 64], sc2[128 + lane + 64]) + a1);
  outf[((size_t)b * 128 + lane) * MQ + m] = r0;
  outf[((size_t)b * 128 + lane + 64) * MQ + m] = r1;
}

// ------------------------------------------------------------------
extern "C" void kernel_launch(void* const* d_in, const int* in_sizes, int n_in,
                              void* d_out, int out_size, void* d_ws, size_t ws_size,
                              hipStream_t stream) {
  (void)in_sizes; (void)n_in; (void)out_size; (void)ws_size;
  const float* p   = (const float*)d_in[0];
  const float* f   = (const float*)d_in[1];
  const float* w1  = (const float*)d_in[2];
  const float* g1  = (const float*)d_in[3];
  const float* b1  = (const float*)d_in[4];
  const float* w2  = (const float*)d_in[5];
  const float* g2  = (const float*)d_in[6];
  const float* b2  = (const float*)d_in[7];
  const float* wsk = (const float*)d_in[8];
  const float* bsk = (const float*)d_in[9];
  float* out = (float*)d_out;
  float* wsf = (float*)d_ws;

  float* gbuf  = wsf + WS_G;
  int*   nidx  = (int*)(wsf + WS_NIDX);
  int*   idxi  = (int*)(wsf + WS_IDXI);
  float* st1   = wsf + WS_ST1;
  float* st2   = wsf + WS_ST2;
  float* sc1   = wsf + WS_SC1;
  float* sc2   = wsf + WS_SC2;
  float* maxy2 = wsf + WS_MAXY2;

  float* out_newp = out;
  float* out_f    = out + BB*MQ*3;

  // zero the atomic stats accumulators (st1+st2 are contiguous)
  (void)hipMemsetAsync(st1, 0, (8192 + 16384) * sizeof(float), stream);

  // fused: blocks 0..3 FPS, 4..515 g-precompute (in fps shadow)
  fps_fused_kernel<<<4 + 512, FPS_T, 0, stream>>>(p, out, idxi, f, gbuf, w1);
  ballq_kernel<<<BB*MQ/4, 256, 0, stream>>>(p, out_newp, nidx);
  p1_kernel<<<BB*MQ/4, 256, 0, stream>>>(gbuf, out_newp, w1, nidx, st1);
  fin1_kernel<<<1, 64, 0, stream>>>(st1, g1, b1, sc1);
  p2_kernel<<<BB*MQ/4, 256, 0, stream>>>(gbuf, out_newp, w1, w2, nidx, sc1, st2, maxy2);
  fin2_kernel<<<1, 128, 0, stream>>>(st2, g2, b2, sc2);
  p3_kernel<<<BB*MQ/4, 256, 0, stream>>>(f, idxi, wsk, bsk, sc2, maxy2, out_f);
}